// Round 13
// baseline (5346.112 us; speedup 1.0000x reference)
//
#include <hip/hip_runtime.h>
#include <math.h>

#define BB   2048
#define NN_  768
#define MM   3072
#define LAMBD 0.1f

typedef __attribute__((ext_vector_type(8))) _Float16 half8;
typedef __attribute__((ext_vector_type(4))) float  f32x4;
typedef __attribute__((ext_vector_type(4))) unsigned short us4;

union HB { _Float16 f; unsigned short u; };
struct HL { unsigned short h, l; };

__device__ __forceinline__ unsigned short h_bits(float f) {
    HB b; b.f = (_Float16)f; return b.u;
}
__device__ __forceinline__ HL split2h(float f) {
    HL r;
    HB b; b.f = (_Float16)f;
    r.h = b.u;
    const float fh = (float)b.f;
    HB c; c.f = (_Float16)(f - fh);
    r.l = c.u;
    return r;
}
__device__ __forceinline__ float clampl(float x) {
    return fminf(fmaxf(x, -LAMBD), LAMBD);
}

// ---------------------------------------------------------------------------
// Split-K small GEMM (768x768 out, fp16 3-term), 64x64 tile, 4 waves 2x2.
// GLOBAL-DIRECT fragments (operands L2/L3-resident; no LDS staging, no
// K-loop barriers). A pre-split fp16 h/l; B pre-split fp16 h/l ([col][k]).
// Grid: (12, 12, KS). Writes f32 partials P[ks*768^2 + idx].
// ---------------------------------------------------------------------------
__global__ __launch_bounds__(256)
void gemm_sk(const unsigned short* __restrict__ Ah,
             const unsigned short* __restrict__ Al,
             int lda,
             const unsigned short* __restrict__ Bh,
             const unsigned short* __restrict__ Bl,
             int ldb,
             float* __restrict__ P, int Kper)
{
    __shared__ __align__(16) float eb[64 * 65];

    const int tid  = threadIdx.x;
    const int brow = blockIdx.y * 64;
    const int bcol = blockIdx.x * 64;
    const int koff = blockIdx.z * Kper;
    const int wave = tid >> 6, lane = tid & 63;
    const int wr = wave >> 1, wc = wave & 1;
    const int lrow = lane & 15, kg = lane >> 4;

    const int rA0 = brow + wr * 32 + lrow;
    const int cB0 = bcol + wc * 32 + lrow;
    const int kb  = koff + kg * 8;

    size_t a0 = (size_t)rA0 * lda + kb;
    size_t a1 = (size_t)(rA0 + 16) * lda + kb;
    size_t b0 = (size_t)cB0 * ldb + kb;
    size_t b1 = (size_t)(cB0 + 16) * ldb + kb;

    f32x4 acc[2][2];
    #pragma unroll
    for (int m = 0; m < 2; ++m)
        #pragma unroll
        for (int n = 0; n < 2; ++n)
            #pragma unroll
            for (int q = 0; q < 4; ++q) acc[m][n][q] = 0.0f;

    const int NK = Kper / 32;
    #pragma unroll 2
    for (int ki = 0; ki < NK; ++ki) {
        half8 ah[2], al[2], bh[2], bl[2];
        ah[0] = *(const half8*)(Ah + a0);  al[0] = *(const half8*)(Al + a0);
        ah[1] = *(const half8*)(Ah + a1);  al[1] = *(const half8*)(Al + a1);
        bh[0] = *(const half8*)(Bh + b0);  bl[0] = *(const half8*)(Bl + b0);
        bh[1] = *(const half8*)(Bh + b1);  bl[1] = *(const half8*)(Bl + b1);
        #pragma unroll
        for (int m = 0; m < 2; ++m)
            #pragma unroll
            for (int n = 0; n < 2; ++n) {
                acc[m][n] = __builtin_amdgcn_mfma_f32_16x16x32_f16(ah[m], bh[n], acc[m][n], 0, 0, 0);
                acc[m][n] = __builtin_amdgcn_mfma_f32_16x16x32_f16(ah[m], bl[n], acc[m][n], 0, 0, 0);
                acc[m][n] = __builtin_amdgcn_mfma_f32_16x16x32_f16(al[m], bh[n], acc[m][n], 0, 0, 0);
            }
        a0 += 32; a1 += 32; b0 += 32; b1 += 32;
    }

    // transposed epilogue: acc -> LDS [64][65] -> coalesced float4 rows
    #pragma unroll
    for (int m = 0; m < 2; ++m)
        #pragma unroll
        for (int n = 0; n < 2; ++n)
            #pragma unroll
            for (int r = 0; r < 4; ++r)
                eb[(wr * 32 + m * 16 + kg * 4 + r) * 65 + wc * 32 + n * 16 + lrow] = acc[m][n][r];
    __syncthreads();
    float* Pk = P + (size_t)blockIdx.z * NN_ * NN_;
    #pragma unroll
    for (int j = 0; j < 4; ++j) {
        const int row = wave * 16 + j * 4 + (lane >> 4);
        const int col = (lane & 15) * 4;
        const float4 v = *(const float4*)&eb[row * 65 + col];
        *(float4*)(Pk + (size_t)(brow + row) * NN_ + bcol + col) = v;
    }
}

// Reduce 4 split-K partials with epilogue. MODE: 0 plain, 1 +I, 2 2*E1-sum.
// Writes f32 C and fp16 h/l Ch/Cl.
template<int MODE>
__global__ __launch_bounds__(256)
void red_ns(const float* __restrict__ P,
            const float* __restrict__ E1,
            float* __restrict__ C,
            unsigned short* __restrict__ Ch,
            unsigned short* __restrict__ Cl)
{
    const size_t i4 = ((size_t)blockIdx.x * 256 + threadIdx.x) * 4;
    const size_t sz = (size_t)NN_ * NN_;
    float4 s = *(const float4*)(P + i4);
    const float4 s1 = *(const float4*)(P + sz + i4);
    const float4 s2 = *(const float4*)(P + 2 * sz + i4);
    const float4 s3 = *(const float4*)(P + 3 * sz + i4);
    s.x = (s.x + s1.x) + (s2.x + s3.x);
    s.y = (s.y + s1.y) + (s2.y + s3.y);
    s.z = (s.z + s1.z) + (s2.z + s3.z);
    s.w = (s.w + s1.w) + (s2.w + s3.w);
    float v[4] = {s.x, s.y, s.z, s.w};
    if constexpr (MODE == 1) {
        const int row = (int)(i4 / NN_);
        const int col = (int)(i4 - (size_t)row * NN_);
        #pragma unroll
        for (int j = 0; j < 4; ++j) if (row == col + j) v[j] += 1.0f;
    }
    if constexpr (MODE == 2) {
        const float4 e = *(const float4*)(E1 + i4);
        v[0] = 2.0f * e.x - v[0]; v[1] = 2.0f * e.y - v[1];
        v[2] = 2.0f * e.z - v[2]; v[3] = 2.0f * e.w - v[3];
    }
    float4 o; o.x = v[0]; o.y = v[1]; o.z = v[2]; o.w = v[3];
    *(float4*)(C + i4) = o;
    us4 h, l;
    const HL a = split2h(v[0]), b = split2h(v[1]);
    const HL c = split2h(v[2]), d = split2h(v[3]);
    h.x = a.h; l.x = a.l; h.y = b.h; l.y = b.l;
    h.z = c.h; l.z = c.l; h.w = d.h; l.w = d.l;
    *(us4*)(Ch + i4) = h;
    *(us4*)(Cl + i4) = l;
}

// ---------------------------------------------------------------------------
// Big fp16 2-term GEMM: 64x64 tile, 4 waves (32x32), BK=32.
// GLOBAL-DIRECT fragments — no LDS staging, no K-loop barriers; operands are
// L1/L2-resident (kg-groups cover whole 64B lines per row).
// AMODE: 0 f32 A -> cvt in reg; 1 pre-cvt fp16 (Ah); 4 fp16 pair Ah/Ah+psz sum.
// EPI: 0 C=acc f32 (+EMIT); 3 ADMM w-update; 4 fp16 partial -> Y2[cks*ks+gi].
// EMIT: 0 none, 1 Y2=fp16(acc), 2 EH/EL = split fp16(acc).
// Grid: flat NBM*NBN*KS; per-XCD 2D patch PM x PN for L2 reuse.
// ---------------------------------------------------------------------------
template<int NBM, int NBN, int KS, int PM, int PN, int AMODE, int EPI, int EMIT, int LASTZ>
__global__ __launch_bounds__(256)
void gemm_big(const float* __restrict__ A,
              const unsigned short* __restrict__ Ah,
              int lda, size_t psz,
              const unsigned short* __restrict__ Bh,
              const unsigned short* __restrict__ Bl,
              int ldb,
              float* __restrict__ C, int ldc, size_t cks, int Kper,
              const float* __restrict__ F1,
              float* __restrict__ Wio,
              float* __restrict__ OutZ,
              unsigned short* __restrict__ Y2,
              unsigned short* __restrict__ EH,
              unsigned short* __restrict__ EL)
{
    static_assert(NBM % PM == 0 && NBN % PN == 0, "patch divides grid");
    constexpr int XM = NBM / PM, XN = NBN / PN;
    static_assert(XM * XN * KS == 8, "patches x KS must equal 8 XCDs");
    static_assert(PM * PN == (NBM * NBN * KS) / 8, "slot count");

    __shared__ __align__(16) float eb[64 * 65];

    const int bid  = blockIdx.x;
    const int xcd  = bid & 7;
    const int slot = bid >> 3;
    const int ks   = xcd % KS;
    const int rest = xcd / KS;
    const int xn   = rest % XN;
    const int xm   = rest / XN;
    const int m_   = xm * PM + slot / PN;
    const int n_   = xn * PN + slot % PN;
    const int brow = m_ * 64;
    const int bcol = n_ * 64;
    const int koff = ks * Kper;

    const int tid  = threadIdx.x;
    const int wave = tid >> 6, lane = tid & 63;
    const int wr = wave >> 1, wc = wave & 1;
    const int lrow = lane & 15, kg = lane >> 4;

    const int rA0 = brow + wr * 32 + lrow;
    const int cB0 = bcol + wc * 32 + lrow;
    const int kb  = koff + kg * 8;

    size_t a0 = (size_t)rA0 * lda + kb;
    size_t a1 = (size_t)(rA0 + 16) * lda + kb;
    size_t b0 = (size_t)cB0 * ldb + kb;
    size_t b1 = (size_t)(cB0 + 16) * ldb + kb;

    f32x4 acc[2][2];
    #pragma unroll
    for (int m = 0; m < 2; ++m)
        #pragma unroll
        for (int n = 0; n < 2; ++n)
            #pragma unroll
            for (int q = 0; q < 4; ++q) acc[m][n][q] = 0.0f;

    const int NK = Kper / 32;
    #pragma unroll 2
    for (int ki = 0; ki < NK; ++ki) {
        half8 a[2], bh[2], bl[2];
        if constexpr (AMODE == 1) {
            a[0] = *(const half8*)(Ah + a0);
            a[1] = *(const half8*)(Ah + a1);
        } else if constexpr (AMODE == 4) {
            a[0] = *(const half8*)(Ah + a0) + *(const half8*)(Ah + a0 + psz);
            a[1] = *(const half8*)(Ah + a1) + *(const half8*)(Ah + a1 + psz);
        } else {
            const float4 f0 = *(const float4*)(A + a0);
            const float4 f1 = *(const float4*)(A + a0 + 4);
            const float4 g0 = *(const float4*)(A + a1);
            const float4 g1 = *(const float4*)(A + a1 + 4);
            half8 h0, h1;
            h0[0] = (_Float16)f0.x; h0[1] = (_Float16)f0.y;
            h0[2] = (_Float16)f0.z; h0[3] = (_Float16)f0.w;
            h0[4] = (_Float16)f1.x; h0[5] = (_Float16)f1.y;
            h0[6] = (_Float16)f1.z; h0[7] = (_Float16)f1.w;
            h1[0] = (_Float16)g0.x; h1[1] = (_Float16)g0.y;
            h1[2] = (_Float16)g0.z; h1[3] = (_Float16)g0.w;
            h1[4] = (_Float16)g1.x; h1[5] = (_Float16)g1.y;
            h1[6] = (_Float16)g1.z; h1[7] = (_Float16)g1.w;
            a[0] = h0; a[1] = h1;
        }
        bh[0] = *(const half8*)(Bh + b0);  bl[0] = *(const half8*)(Bl + b0);
        bh[1] = *(const half8*)(Bh + b1);  bl[1] = *(const half8*)(Bl + b1);
        #pragma unroll
        for (int m = 0; m < 2; ++m)
            #pragma unroll
            for (int n = 0; n < 2; ++n) {
                acc[m][n] = __builtin_amdgcn_mfma_f32_16x16x32_f16(a[m], bh[n], acc[m][n], 0, 0, 0);
                acc[m][n] = __builtin_amdgcn_mfma_f32_16x16x32_f16(a[m], bl[n], acc[m][n], 0, 0, 0);
            }
        a0 += 32; a1 += 32; b0 += 32; b1 += 32;
    }

    // ---- transposed epilogue: acc -> LDS [64][65] -> whole-row float4 I/O ----
    #pragma unroll
    for (int m = 0; m < 2; ++m)
        #pragma unroll
        for (int n = 0; n < 2; ++n)
            #pragma unroll
            for (int r = 0; r < 4; ++r)
                eb[(wr * 32 + m * 16 + kg * 4 + r) * 65 + wc * 32 + n * 16 + lrow] = acc[m][n][r];
    __syncthreads();

    #pragma unroll
    for (int j = 0; j < 4; ++j) {
        const int row = wave * 16 + j * 4 + (lane >> 4);
        const int col = (lane & 15) * 4;
        const float4 v = *(const float4*)&eb[row * 65 + col];
        const size_t gi = (size_t)(brow + row) * ldc + bcol + col;
        if constexpr (EPI == 0) {
            *(float4*)(C + cks * ks + gi) = v;
            if constexpr (EMIT == 1) {
                us4 h;
                h.x = h_bits(v.x); h.y = h_bits(v.y);
                h.z = h_bits(v.z); h.w = h_bits(v.w);
                *(us4*)(Y2 + gi) = h;
            }
            if constexpr (EMIT == 2) {
                const HL a = split2h(v.x), b = split2h(v.y);
                const HL c2 = split2h(v.z), d = split2h(v.w);
                us4 h, l;
                h.x = a.h; l.x = a.l; h.y = b.h; l.y = b.l;
                h.z = c2.h; l.z = c2.l; h.w = d.h; l.w = d.l;
                *(us4*)(EH + gi) = h;
                *(us4*)(EL + gi) = l;
            }
        } else if constexpr (EPI == 4) {   // fp16 partial write (T-GEMM)
            us4 h;
            h.x = h_bits(v.x); h.y = h_bits(v.y);
            h.z = h_bits(v.z); h.w = h_bits(v.w);
            *(us4*)(Y2 + cks * ks + gi) = h;
        } else { // EPI == 3: ADMM w-update, fully coalesced streams
            const float4 f1 = *(const float4*)(F1 + gi);
            const float4 ww = *(const float4*)(Wio + gi);
            float wn0 = f1.x + ww.x - clampl(ww.x) - v.x;
            float wn1 = f1.y + ww.y - clampl(ww.y) - v.y;
            float wn2 = f1.z + ww.z - clampl(ww.z) - v.z;
            float wn3 = f1.w + ww.w - clampl(ww.w) - v.w;
            if constexpr (LASTZ) {
                float4 o;
                o.x = wn0 - clampl(wn0); o.y = wn1 - clampl(wn1);
                o.z = wn2 - clampl(wn2); o.w = wn3 - clampl(wn3);
                *(float4*)(OutZ + gi) = o;
            } else {
                float4 o; o.x = wn0; o.y = wn1; o.z = wn2; o.w = wn3;
                *(float4*)(Wio + gi) = o;
                us4 h;
                h.x = h_bits(f1.x + wn0 - 2.0f * clampl(wn0));
                h.y = h_bits(f1.y + wn1 - 2.0f * clampl(wn1));
                h.z = h_bits(f1.z + wn2 - 2.0f * clampl(wn2));
                h.w = h_bits(f1.w + wn3 - 2.0f * clampl(wn3));
                *(us4*)(Y2 + gi) = h;
            }
        }
    }
}

// Normalize rows of weight (3072x768); emit fp16 h/l of wn and wn^T.
__global__ __launch_bounds__(256)
void rownorm_kernel(const float* __restrict__ W,
                    unsigned short* __restrict__ wnH, unsigned short* __restrict__ wnL,
                    unsigned short* __restrict__ wnTH, unsigned short* __restrict__ wnTL)
{
    __shared__ float red[256];
    const int row = blockIdx.x;
    const int t = threadIdx.x;
    const float* wr = W + (size_t)row * NN_;
    float s = 0.0f;
    for (int k = t; k < NN_; k += 256) { const float w = wr[k]; s += w * w; }
    red[t] = s; __syncthreads();
    for (int off = 128; off > 0; off >>= 1) {
        if (t < off) red[t] += red[t + off];
        __syncthreads();
    }
    const float rn = 1.0f / sqrtf(red[0]);
    for (int k = t; k < NN_; k += 256) {
        const float v = wr[k] * rn;
        const HL s2 = split2h(v);
        wnH[(size_t)row * NN_ + k] = s2.h;
        wnL[(size_t)row * NN_ + k] = s2.l;
        wnTH[(size_t)k * MM + row] = s2.h;
        wnTL[(size_t)k * MM + row] = s2.l;
    }
}

__global__ __launch_bounds__(256)
void rowabs_kernel(const float* __restrict__ G, float* __restrict__ rowsum)
{
    __shared__ float red[256];
    const int row = blockIdx.x;
    const int t = threadIdx.x;
    const float* gr = G + (size_t)row * NN_;
    float s = 0.0f;
    for (int k = t; k < NN_; k += 256) s += fabsf(gr[k]);
    red[t] = s; __syncthreads();
    for (int off = 128; off > 0; off >>= 1) {
        if (t < off) red[t] += red[t + off];
        __syncthreads();
    }
    if (t == 0) rowsum[row] = red[0];
}

__global__ __launch_bounds__(256)
void cmax_kernel(const float* __restrict__ rowsum, float* __restrict__ cbuf)
{
    __shared__ float red[256];
    const int t = threadIdx.x;
    float mx = 0.0f;
    for (int k = t; k < NN_; k += 256) mx = fmaxf(mx, rowsum[k]);
    red[t] = mx; __syncthreads();
    for (int off = 128; off > 0; off >>= 1) {
        if (t < off) red[t] = fmaxf(red[t], red[t + off]);
        __syncthreads();
    }
    if (t == 0) cbuf[0] = 2.0f / (1.0f + red[0]);
}

// X0 = c*I, plus fp16 h/l emit
__global__ __launch_bounds__(256)
void initdiag_kernel(float* __restrict__ X, unsigned short* __restrict__ XH,
                     unsigned short* __restrict__ XL, const float* __restrict__ c)
{
    const int idx = blockIdx.x * 256 + threadIdx.x;
    const int p = idx / NN_, q = idx - p * NN_;
    const float v = (p == q) ? c[0] : 0.0f;
    X[idx] = v;
    const HL s = split2h(v);
    XH[idx] = s.h;
    XL[idx] = s.l;
}

// dec = p0 + p1 (float4)
__global__ __launch_bounds__(256)
void add2_kernel(const float* __restrict__ p0, size_t ps, float* __restrict__ o)
{
    const size_t i = ((size_t)blockIdx.x * 256 + threadIdx.x) * 4;
    const float4 a = *(const float4*)(p0 + i);
    const float4 b = *(const float4*)(p0 + ps + i);
    float4 v;
    v.x = a.x + b.x; v.y = a.y + b.y;
    v.z = a.z + b.z; v.w = a.w + b.w;
    *(float4*)(o + i) = v;
}

extern "C" void kernel_launch(void* const* d_in, const int* in_sizes, int n_in,
                              void* d_out, int out_size, void* d_ws, size_t ws_size,
                              hipStream_t stream)
{
    const float* x = (const float*)d_in[0];   // (2048, 768)
    const float* w = (const float*)d_in[1];   // (3072, 768)

    float* out = (float*)d_out;
    float* z   = out;                          // (2048, 3072)
    float* dec = out + (size_t)BB * MM;        // (2048, 768)

    char* wsb = (char*)d_ws;
    size_t off = 0;
    auto alloc = [&](size_t bytes) -> void* {
        void* p = wsb + off;
        off += (bytes + 255) & ~(size_t)255;
        return p;
    };
    // --- persistent ---
    unsigned short* wnH  = (unsigned short*)alloc((size_t)MM * NN_ * 2);
    unsigned short* wnL  = (unsigned short*)alloc((size_t)MM * NN_ * 2);
    unsigned short* wnTH = (unsigned short*)alloc((size_t)MM * NN_ * 2);
    unsigned short* wnTL = (unsigned short*)alloc((size_t)MM * NN_ * 2);
    float* adotb = (float*)alloc((size_t)BB * MM * 4);
    float* wbuf  = (float*)alloc((size_t)BB * MM * 4);
    unsigned short* y2h = (unsigned short*)alloc((size_t)BB * MM * 2);
    unsigned short* RTH = (unsigned short*)alloc((size_t)MM * NN_ * 2);
    unsigned short* RTL = (unsigned short*)alloc((size_t)MM * NN_ * 2);
    unsigned short* Thp = (unsigned short*)alloc((size_t)2 * BB * NN_ * 2); // fp16 T partials
    // X h/l ping-pong (persistent: final pair = Ginv h/l, read during RT while
    // Tp overwrites the overlay region)
    unsigned short* XH0 = (unsigned short*)alloc((size_t)NN_ * NN_ * 2);
    unsigned short* XL0 = (unsigned short*)alloc((size_t)NN_ * NN_ * 2);
    unsigned short* XH1 = (unsigned short*)alloc((size_t)NN_ * NN_ * 2);
    unsigned short* XL1 = (unsigned short*)alloc((size_t)NN_ * NN_ * 2);
    // --- overlay: NS temps (dead after RT) aliased with Tp (decode/RT scratch) ---
    const size_t overlay = off;
    float* G  = (float*)alloc((size_t)NN_ * NN_ * 4);
    unsigned short* GH  = (unsigned short*)alloc((size_t)NN_ * NN_ * 2);
    unsigned short* GL  = (unsigned short*)alloc((size_t)NN_ * NN_ * 2);
    float* X0 = (float*)alloc((size_t)NN_ * NN_ * 4);
    float* X1 = (float*)alloc((size_t)NN_ * NN_ * 4);
    float* Yb = (float*)alloc((size_t)NN_ * NN_ * 4);
    unsigned short* YbH = (unsigned short*)alloc((size_t)NN_ * NN_ * 2);
    unsigned short* YbL = (unsigned short*)alloc((size_t)NN_ * NN_ * 2);
    float* rowsum = (float*)alloc(NN_ * 4);
    float* cbuf   = (float*)alloc(256);
    float* Pp = (float*)alloc((size_t)4 * NN_ * NN_ * 4);  // split-K f32 partials
    // Tp (2 x 2048x768 f32 = 12.6 MB) aliases the NS-temp region (~14.2 MB);
    // NS temps dead before first Tp use (RT GEMM f32 scratch / decode partials).
    float* Tp = (float*)(wsb + overlay);
    const size_t TPS = (size_t)BB * NN_;

    (void)hipMemsetAsync(wbuf, 0, (size_t)BB * MM * sizeof(float), stream);

    const dim3 blk(256);
    const dim3 gsk(NN_ / 64, NN_ / 64, 4);
    const int  RED = (NN_ * NN_ / 4) / 256;   // 576

    rownorm_kernel<<<MM, blk, 0, stream>>>(w, wnH, wnL, wnTH, wnTL);

    // adotb = x @ wn^T (M2048 N3072 K768); emit y2_0 = fp16(adotb)
    gemm_big<32,48,1,8,24,0,0,1,0><<<1536, blk, 0, stream>>>(
        x, nullptr, NN_, 0, wnH, wnL, NN_, adotb, MM, 0, NN_,
        nullptr, nullptr, nullptr, y2h, nullptr, nullptr);

    // G = wn^T wn + I (768x768, K=3072), split-K=4 + reduce(+I, split)
    gemm_sk<<<gsk, blk, 0, stream>>>(
        wnTH, wnTL, MM, wnTH, wnTL, MM, Pp, MM / 4);
    red_ns<1><<<RED, blk, 0, stream>>>(Pp, nullptr, G, GH, GL);

    rowabs_kernel<<<NN_, blk, 0, stream>>>(G, rowsum);
    cmax_kernel<<<1, blk, 0, stream>>>(rowsum, cbuf);
    initdiag_kernel<<<(NN_ * NN_) / 256, blk, 0, stream>>>(X0, XH0, XL0, cbuf);

    // Newton-Schulz X <- 2X - XGX, 7 iterations, split-K=4, all-fp16 operands
    float* Xc = X0;  unsigned short* XcH = XH0;  unsigned short* XcL = XL0;
    float* Xn = X1;  unsigned short* XnH = XH1;  unsigned short* XnL = XL1;
    for (int it = 0; it < 7; ++it) {
        // Yb = Xc @ G
        gemm_sk<<<gsk, blk, 0, stream>>>(
            XcH, XcL, NN_, GH, GL, NN_, Pp, NN_ / 4);
        red_ns<0><<<RED, blk, 0, stream>>>(Pp, nullptr, Yb, YbH, YbL);
        // Xn = 2*Xc - Xc @ Yb
        gemm_sk<<<gsk, blk, 0, stream>>>(
            XcH, XcL, NN_, YbH, YbL, NN_, Pp, NN_ / 4);
        red_ns<2><<<RED, blk, 0, stream>>>(Pp, Xc, Xn, XnH, XnL);
        float* tf = Xc; Xc = Xn; Xn = tf;
        unsigned short* th = XcH; XcH = XnH; XnH = th;
        unsigned short* tl = XcL; XcL = XnL; XnL = tl;
    }
    // XcH/XcL = fp16 split of G^{-1}

    // RT = wn @ Ginv (M3072 N768 K768); emit RTH/RTL (f32 scratch to Tp)
    gemm_big<48,12,1,12,6,1,0,2,0><<<576, blk, 0, stream>>>(
        nullptr, wnH, NN_, 0, XcH, XcL, NN_, Tp, NN_, 0, NN_,
        nullptr, nullptr, nullptr, nullptr, RTH, RTL);

    // ADMM loop: T = y2 @ wn -> fp16 partials Thp (KS=2);
    // w-update sums the fp16 pair in-register (AMODE=4)
    for (int it = 0; it < 20; ++it) {
        gemm_big<32,12,2,16,6,1,4,0,0><<<768, blk, 0, stream>>>(
            nullptr, y2h, MM, 0, wnTH, wnTL, MM, nullptr, NN_, TPS, MM / 2,
            nullptr, nullptr, nullptr, Thp, nullptr, nullptr);
        if (it < 19) {
            gemm_big<32,48,1,8,24,4,3,0,0><<<1536, blk, 0, stream>>>(
                nullptr, Thp, NN_, TPS, RTH, RTL, NN_, nullptr, MM, 0, NN_,
                adotb, wbuf, nullptr, y2h, nullptr, nullptr);
        } else {
            gemm_big<32,48,1,8,24,4,3,0,1><<<1536, blk, 0, stream>>>(
                nullptr, Thp, NN_, TPS, RTH, RTL, NN_, nullptr, MM, 0, NN_,
                adotb, wbuf, z, nullptr, nullptr, nullptr);
        }
    }

    // decoded = z @ wn (M2048 N768 K3072), KS=2 f32 partials + reduce
    gemm_big<32,12,2,16,6,0,0,0,0><<<768, blk, 0, stream>>>(
        z, nullptr, MM, 0, wnTH, wnTL, MM, Tp, NN_, TPS, MM / 2,
        nullptr, nullptr, nullptr, nullptr, nullptr, nullptr);
    add2_kernel<<<(BB * NN_ / 4) / 256, blk, 0, stream>>>(Tp, TPS, dec);
}

// Round 14
// 3122.046 us; speedup vs baseline: 1.7124x; 1.7124x over previous
//
#include <hip/hip_runtime.h>
#include <math.h>

#define BB   2048
#define NN_  768
#define MM   3072
#define LAMBD 0.1f

typedef __attribute__((ext_vector_type(8))) _Float16 half8;
typedef __attribute__((ext_vector_type(4))) float  f32x4;
typedef __attribute__((ext_vector_type(4))) unsigned short us4;

union HB { _Float16 f; unsigned short u; };
struct HL { unsigned short h, l; };

__device__ __forceinline__ unsigned short h_bits(float f) {
    HB b; b.f = (_Float16)f; return b.u;
}
__device__ __forceinline__ HL split2h(float f) {
    HL r;
    HB b; b.f = (_Float16)f;
    r.h = b.u;
    const float fh = (float)b.f;
    HB c; c.f = (_Float16)(f - fh);
    r.l = c.u;
    return r;
}
__device__ __forceinline__ float clampl(float x) {
    return fminf(fmaxf(x, -LAMBD), LAMBD);
}

// ---------------------------------------------------------------------------
// Split-K small GEMM (768x768 out, fp16 3-term), 64x64 tile, reg-prefetch,
// single LDS buffer + transposed (coalesced) epilogue. Grid: (12, 12, KS).
// (R12-proven form.)
// ---------------------------------------------------------------------------
template<int APRE>
__global__ __launch_bounds__(256)
void gemm_sk(const float* __restrict__ A,
             const unsigned short* __restrict__ Ah,
             const unsigned short* __restrict__ Al,
             int lda,
             const unsigned short* __restrict__ Bh,
             const unsigned short* __restrict__ Bl,
             int ldb,
             float* __restrict__ P, int Kper)
{
    __shared__ __align__(16) char smem[20480];
    unsigned short (*AsH)[40] = (unsigned short (*)[40])(smem);
    unsigned short (*AsL)[40] = (unsigned short (*)[40])(smem + 5120);
    unsigned short (*BsH)[40] = (unsigned short (*)[40])(smem + 10240);
    unsigned short (*BsL)[40] = (unsigned short (*)[40])(smem + 15360);

    const int tid  = threadIdx.x;
    const int brow = blockIdx.y * 64;
    const int bcol = blockIdx.x * 64;
    const int koff = blockIdx.z * Kper;
    const int wave = tid >> 6, lane = tid & 63;
    const int wr = wave >> 1, wc = wave & 1;
    const int lrow = lane & 15, kg = lane >> 4;

    const int sk4  = (tid & 7) << 2;

    us4   rAh[2], rAl[2], rBh[2], rBl[2];
    float4 rAf[2];

    auto LOAD = [&](int k0) {
        #pragma unroll
        for (int p = 0; p < 2; ++p) {
            const int row = (p * 256 + tid) >> 3;
            const size_t ga = (size_t)(brow + row) * lda + k0 + sk4;
            const size_t gb = (size_t)(bcol + row) * ldb + k0 + sk4;
            if constexpr (APRE) {
                rAh[p] = *(const us4*)(Ah + ga);
                rAl[p] = *(const us4*)(Al + ga);
            } else {
                rAf[p] = *(const float4*)(A + ga);
            }
            rBh[p] = *(const us4*)(Bh + gb);
            rBl[p] = *(const us4*)(Bl + gb);
        }
    };
    auto STORE = [&]() {
        #pragma unroll
        for (int p = 0; p < 2; ++p) {
            const int row = (p * 256 + tid) >> 3;
            if constexpr (APRE) {
                *(us4*)&AsH[row][sk4] = rAh[p];
                *(us4*)&AsL[row][sk4] = rAl[p];
            } else {
                const HL sx = split2h(rAf[p].x), sy = split2h(rAf[p].y);
                const HL sz = split2h(rAf[p].z), sw = split2h(rAf[p].w);
                us4 h, l;
                h.x = sx.h; l.x = sx.l; h.y = sy.h; l.y = sy.l;
                h.z = sz.h; l.z = sz.l; h.w = sw.h; l.w = sw.l;
                *(us4*)&AsH[row][sk4] = h;
                *(us4*)&AsL[row][sk4] = l;
            }
            *(us4*)&BsH[row][sk4] = rBh[p];
            *(us4*)&BsL[row][sk4] = rBl[p];
        }
    };

    f32x4 acc[2][2];
    #pragma unroll
    for (int m = 0; m < 2; ++m)
        #pragma unroll
        for (int n = 0; n < 2; ++n)
            #pragma unroll
            for (int q = 0; q < 4; ++q) acc[m][n][q] = 0.0f;

    const int NK = Kper / 32;
    LOAD(koff);
    STORE();
    __syncthreads();

    for (int ki = 0; ki < NK; ++ki) {
        if (ki + 1 < NK) LOAD(koff + (ki + 1) * 32);

        half8 ahi[2], alo[2], bhi[2], blo[2];
        #pragma unroll
        for (int m = 0; m < 2; ++m) {
            const int r = wr * 32 + m * 16 + lrow;
            ahi[m] = *(const half8*)&AsH[r][kg * 8];
            alo[m] = *(const half8*)&AsL[r][kg * 8];
        }
        #pragma unroll
        for (int n = 0; n < 2; ++n) {
            const int c = wc * 32 + n * 16 + lrow;
            bhi[n] = *(const half8*)&BsH[c][kg * 8];
            blo[n] = *(const half8*)&BsL[c][kg * 8];
        }
        #pragma unroll
        for (int m = 0; m < 2; ++m)
            #pragma unroll
            for (int n = 0; n < 2; ++n) {
                acc[m][n] = __builtin_amdgcn_mfma_f32_16x16x32_f16(ahi[m], bhi[n], acc[m][n], 0, 0, 0);
                acc[m][n] = __builtin_amdgcn_mfma_f32_16x16x32_f16(ahi[m], blo[n], acc[m][n], 0, 0, 0);
                acc[m][n] = __builtin_amdgcn_mfma_f32_16x16x32_f16(alo[m], bhi[n], acc[m][n], 0, 0, 0);
            }
        __syncthreads();
        if (ki + 1 < NK) { STORE(); __syncthreads(); }
    }

    // transposed epilogue: acc -> LDS [64][65] -> coalesced float4 rows
    float* eb = (float*)smem;
    #pragma unroll
    for (int m = 0; m < 2; ++m)
        #pragma unroll
        for (int n = 0; n < 2; ++n)
            #pragma unroll
            for (int r = 0; r < 4; ++r)
                eb[(wr * 32 + m * 16 + kg * 4 + r) * 65 + wc * 32 + n * 16 + lrow] = acc[m][n][r];
    __syncthreads();
    float* Pk = P + (size_t)blockIdx.z * NN_ * NN_;
    #pragma unroll
    for (int j = 0; j < 4; ++j) {
        const int row = wave * 16 + j * 4 + (lane >> 4);
        const int col = (lane & 15) * 4;
        const float4 v = *(const float4*)&eb[row * 65 + col];
        *(float4*)(Pk + (size_t)(brow + row) * NN_ + bcol + col) = v;
    }
}

// Reduce 4 split-K partials with epilogue. MODE: 0 plain, 1 +I, 2 2*E1-sum.
template<int MODE>
__global__ __launch_bounds__(256)
void red_ns(const float* __restrict__ P,
            const float* __restrict__ E1,
            float* __restrict__ C,
            unsigned short* __restrict__ Ch,
            unsigned short* __restrict__ Cl)
{
    const size_t i4 = ((size_t)blockIdx.x * 256 + threadIdx.x) * 4;
    const size_t sz = (size_t)NN_ * NN_;
    float4 s = *(const float4*)(P + i4);
    const float4 s1 = *(const float4*)(P + sz + i4);
    const float4 s2 = *(const float4*)(P + 2 * sz + i4);
    const float4 s3 = *(const float4*)(P + 3 * sz + i4);
    s.x = (s.x + s1.x) + (s2.x + s3.x);
    s.y = (s.y + s1.y) + (s2.y + s3.y);
    s.z = (s.z + s1.z) + (s2.z + s3.z);
    s.w = (s.w + s1.w) + (s2.w + s3.w);
    float v[4] = {s.x, s.y, s.z, s.w};
    if constexpr (MODE == 1) {
        const int row = (int)(i4 / NN_);
        const int col = (int)(i4 - (size_t)row * NN_);
        #pragma unroll
        for (int j = 0; j < 4; ++j) if (row == col + j) v[j] += 1.0f;
    }
    if constexpr (MODE == 2) {
        const float4 e = *(const float4*)(E1 + i4);
        v[0] = 2.0f * e.x - v[0]; v[1] = 2.0f * e.y - v[1];
        v[2] = 2.0f * e.z - v[2]; v[3] = 2.0f * e.w - v[3];
    }
    float4 o; o.x = v[0]; o.y = v[1]; o.z = v[2]; o.w = v[3];
    *(float4*)(C + i4) = o;
    us4 h, l;
    const HL a = split2h(v[0]), b = split2h(v[1]);
    const HL c = split2h(v[2]), d = split2h(v[3]);
    h.x = a.h; l.x = a.l; h.y = b.h; l.y = b.l;
    h.z = c.h; l.z = c.l; h.w = d.h; l.w = d.l;
    *(us4*)(Ch + i4) = h;
    *(us4*)(Cl + i4) = l;
}

// ---------------------------------------------------------------------------
// Big fp16 2-term GEMM: 64xBN tile (BN=64 or 128), 4 waves (32 x BN/2), BK=32,
// reg-prefetch, single LDS buffer + transposed (coalesced) epilogue in
// 64-col half-passes.
// AMODE: 0 f32 A -> cvt; 1 pre-cvt fp16 (Ah); 4 fp16 pair Ah/Ah+psz summed.
// EPI: 0 C=acc f32 (+EMIT); 3 ADMM w-update; 4 fp16 partial -> Y2[cks*ks+gi].
// EMIT: 0 none, 1 Y2=fp16(acc), 2 EH/EL = split fp16(acc).
// Grid: flat NBM*NBN*KS; per-XCD 2D patch PM x PN for L2 reuse.
// ---------------------------------------------------------------------------
template<int BN, int NBM, int NBN, int KS, int PM, int PN, int AMODE, int EPI, int EMIT, int LASTZ>
__global__ __launch_bounds__(256)
void gemm_big(const float* __restrict__ A,
              const unsigned short* __restrict__ Ah,
              int lda, size_t psz,
              const unsigned short* __restrict__ Bh,
              const unsigned short* __restrict__ Bl,
              int ldb,
              float* __restrict__ C, int ldc, size_t cks, int Kper,
              const float* __restrict__ F1,
              float* __restrict__ Wio,
              float* __restrict__ OutZ,
              unsigned short* __restrict__ Y2,
              unsigned short* __restrict__ EH,
              unsigned short* __restrict__ EL)
{
    static_assert(NBM % PM == 0 && NBN % PN == 0, "patch divides grid");
    constexpr int XM = NBM / PM, XN = NBN / PN;
    static_assert(XM * XN * KS == 8, "patches x KS must equal 8 XCDs");
    static_assert(PM * PN == (NBM * NBN * KS) / 8, "slot count");
    constexpr int NF = BN / 32;           // n-frags per wave
    constexpr int CB = BN / 64;           // b-col batches per thread
    constexpr int SM_STAGE = 5120 + 2 * BN * 80;
    constexpr int SM_EPI   = 64 * 68 * 4;
    constexpr int SM_SIZE  = SM_STAGE > SM_EPI ? SM_STAGE : SM_EPI;

    __shared__ __align__(16) char smem[SM_SIZE];
    unsigned short (*AsH)[40] = (unsigned short (*)[40])(smem);
    unsigned short (*BsH)[40] = (unsigned short (*)[40])(smem + 5120);
    unsigned short (*BsL)[40] = (unsigned short (*)[40])(smem + 5120 + BN * 80);

    const int bid  = blockIdx.x;
    const int xcd  = bid & 7;
    const int slot = bid >> 3;
    const int ks   = xcd % KS;
    const int rest = xcd / KS;
    const int xn   = rest % XN;
    const int xm   = rest / XN;
    const int m_   = xm * PM + slot / PN;
    const int n_   = xn * PN + slot % PN;
    const int brow = m_ * 64;
    const int bcol = n_ * BN;
    const int koff = ks * Kper;

    const int tid  = threadIdx.x;
    const int wave = tid >> 6, lane = tid & 63;
    const int wr = wave >> 1, wc = wave & 1;
    const int lrow = lane & 15, kg = lane >> 4;

    const int srow = tid >> 2, sk8 = (tid & 3) << 3;

    uint4  pA0, pA1, pB0[CB], pB1[CB];
    float4 pF[2], pG[2];

    auto LOAD = [&](int k0) {
        const size_t ga = (size_t)(brow + srow) * lda + k0 + sk8;
        if constexpr (AMODE == 1) {
            pA0 = *(const uint4*)(Ah + ga);
        } else if constexpr (AMODE == 4) {
            pA0 = *(const uint4*)(Ah + ga);
            pA1 = *(const uint4*)(Ah + ga + psz);
        } else {
            pF[0] = *(const float4*)(A + ga);
            pF[1] = *(const float4*)(A + ga + 4);
        }
        #pragma unroll
        for (int cb = 0; cb < CB; ++cb) {
            const size_t gb = (size_t)(bcol + cb * 64 + srow) * ldb + k0 + sk8;
            pB0[cb] = *(const uint4*)(Bh + gb);
            pB1[cb] = *(const uint4*)(Bl + gb);
        }
    };
    auto STORE = [&]() {
        if constexpr (AMODE == 1) {
            *(uint4*)&AsH[srow][sk8] = pA0;
        } else if constexpr (AMODE == 4) {
            half8 h0 = *(half8*)&pA0;
            half8 h1 = *(half8*)&pA1;
            half8 hs = h0 + h1;
            *(half8*)&AsH[srow][sk8] = hs;
        } else {
            float va[8];
            va[0] = pF[0].x; va[1] = pF[0].y; va[2] = pF[0].z; va[3] = pF[0].w;
            va[4] = pF[1].x; va[5] = pF[1].y; va[6] = pF[1].z; va[7] = pF[1].w;
            half8 h0;
            #pragma unroll
            for (int j = 0; j < 8; ++j) h0[j] = (_Float16)va[j];
            *(half8*)&AsH[srow][sk8] = h0;
        }
        #pragma unroll
        for (int cb = 0; cb < CB; ++cb) {
            *(uint4*)&BsH[cb * 64 + srow][sk8] = pB0[cb];
            *(uint4*)&BsL[cb * 64 + srow][sk8] = pB1[cb];
        }
    };

    f32x4 acc[2][NF];
    #pragma unroll
    for (int m = 0; m < 2; ++m)
        #pragma unroll
        for (int n = 0; n < NF; ++n)
            #pragma unroll
            for (int q = 0; q < 4; ++q) acc[m][n][q] = 0.0f;

    const int NK = Kper / 32;
    LOAD(koff);
    STORE();
    __syncthreads();

    for (int ki = 0; ki < NK; ++ki) {
        if (ki + 1 < NK) LOAD(koff + (ki + 1) * 32);

        half8 a[2], bh[NF], bl[NF];
        #pragma unroll
        for (int m = 0; m < 2; ++m)
            a[m] = *(const half8*)&AsH[wr * 32 + m * 16 + lrow][kg * 8];
        #pragma unroll
        for (int n = 0; n < NF; ++n) {
            const int c = wc * (BN / 2) + n * 16 + lrow;
            bh[n] = *(const half8*)&BsH[c][kg * 8];
            bl[n] = *(const half8*)&BsL[c][kg * 8];
        }
        #pragma unroll
        for (int m = 0; m < 2; ++m)
            #pragma unroll
            for (int n = 0; n < NF; ++n) {
                acc[m][n] = __builtin_amdgcn_mfma_f32_16x16x32_f16(a[m], bh[n], acc[m][n], 0, 0, 0);
                acc[m][n] = __builtin_amdgcn_mfma_f32_16x16x32_f16(a[m], bl[n], acc[m][n], 0, 0, 0);
            }
        __syncthreads();
        if (ki + 1 < NK) { STORE(); __syncthreads(); }
    }

    // ---- transposed epilogue, 64-col half-passes through LDS [64][68] ----
    float* eb = (float*)smem;
    #pragma unroll
    for (int nh = 0; nh < CB; ++nh) {
        if (nh > 0) __syncthreads();
        #pragma unroll
        for (int m = 0; m < 2; ++m)
            #pragma unroll
            for (int n = 0; n < NF; ++n) {
                const int cg = wc * (BN / 2) + n * 16;
                if ((cg >> 6) == nh) {
                    #pragma unroll
                    for (int r = 0; r < 4; ++r)
                        eb[(wr * 32 + m * 16 + kg * 4 + r) * 68 + (cg & 63) + lrow] = acc[m][n][r];
                }
            }
        __syncthreads();

        #pragma unroll
        for (int j = 0; j < 4; ++j) {
            const int row = wave * 16 + j * 4 + (lane >> 4);
            const int col = (lane & 15) * 4;
            const float4 v = *(const float4*)&eb[row * 68 + col];
            const size_t gi = (size_t)(brow + row) * ldc + bcol + nh * 64 + col;
            if constexpr (EPI == 0) {
                *(float4*)(C + cks * ks + gi) = v;
                if constexpr (EMIT == 1) {
                    us4 h;
                    h.x = h_bits(v.x); h.y = h_bits(v.y);
                    h.z = h_bits(v.z); h.w = h_bits(v.w);
                    *(us4*)(Y2 + gi) = h;
                }
                if constexpr (EMIT == 2) {
                    const HL a2 = split2h(v.x), b2 = split2h(v.y);
                    const HL c2 = split2h(v.z), d2 = split2h(v.w);
                    us4 h, l;
                    h.x = a2.h; l.x = a2.l; h.y = b2.h; l.y = b2.l;
                    h.z = c2.h; l.z = c2.l; h.w = d2.h; l.w = d2.l;
                    *(us4*)(EH + gi) = h;
                    *(us4*)(EL + gi) = l;
                }
            } else if constexpr (EPI == 4) {   // fp16 partial write (T-GEMM)
                us4 h;
                h.x = h_bits(v.x); h.y = h_bits(v.y);
                h.z = h_bits(v.z); h.w = h_bits(v.w);
                *(us4*)(Y2 + cks * ks + gi) = h;
            } else { // EPI == 3: ADMM w-update, fully coalesced streams
                const float4 f1 = *(const float4*)(F1 + gi);
                const float4 ww = *(const float4*)(Wio + gi);
                float wn0 = f1.x + ww.x - clampl(ww.x) - v.x;
                float wn1 = f1.y + ww.y - clampl(ww.y) - v.y;
                float wn2 = f1.z + ww.z - clampl(ww.z) - v.z;
                float wn3 = f1.w + ww.w - clampl(ww.w) - v.w;
                if constexpr (LASTZ) {
                    float4 o;
                    o.x = wn0 - clampl(wn0); o.y = wn1 - clampl(wn1);
                    o.z = wn2 - clampl(wn2); o.w = wn3 - clampl(wn3);
                    *(float4*)(OutZ + gi) = o;
                } else {
                    float4 o; o.x = wn0; o.y = wn1; o.z = wn2; o.w = wn3;
                    *(float4*)(Wio + gi) = o;
                    us4 h;
                    h.x = h_bits(f1.x + wn0 - 2.0f * clampl(wn0));
                    h.y = h_bits(f1.y + wn1 - 2.0f * clampl(wn1));
                    h.z = h_bits(f1.z + wn2 - 2.0f * clampl(wn2));
                    h.w = h_bits(f1.w + wn3 - 2.0f * clampl(wn3));
                    *(us4*)(Y2 + gi) = h;
                }
            }
        }
    }
}

// Normalize rows of weight (3072x768); emit fp16 h/l of wn and wn^T.
__global__ __launch_bounds__(256)
void rownorm_kernel(const float* __restrict__ W,
                    unsigned short* __restrict__ wnH, unsigned short* __restrict__ wnL,
                    unsigned short* __restrict__ wnTH, unsigned short* __restrict__ wnTL)
{
    __shared__ float red[256];
    const int row = blockIdx.x;
    const int t = threadIdx.x;
    const float* wr = W + (size_t)row * NN_;
    float s = 0.0f;
    for (int k = t; k < NN_; k += 256) { const float w = wr[k]; s += w * w; }
    red[t] = s; __syncthreads();
    for (int off = 128; off > 0; off >>= 1) {
        if (t < off) red[t] += red[t + off];
        __syncthreads();
    }
    const float rn = 1.0f / sqrtf(red[0]);
    for (int k = t; k < NN_; k += 256) {
        const float v = wr[k] * rn;
        const HL s2 = split2h(v);
        wnH[(size_t)row * NN_ + k] = s2.h;
        wnL[(size_t)row * NN_ + k] = s2.l;
        wnTH[(size_t)k * MM + row] = s2.h;
        wnTL[(size_t)k * MM + row] = s2.l;
    }
}

__global__ __launch_bounds__(256)
void rowabs_kernel(const float* __restrict__ G, float* __restrict__ rowsum)
{
    __shared__ float red[256];
    const int row = blockIdx.x;
    const int t = threadIdx.x;
    const float* gr = G + (size_t)row * NN_;
    float s = 0.0f;
    for (int k = t; k < NN_; k += 256) s += fabsf(gr[k]);
    red[t] = s; __syncthreads();
    for (int off = 128; off > 0; off >>= 1) {
        if (t < off) red[t] += red[t + off];
        __syncthreads();
    }
    if (t == 0) rowsum[row] = red[0];
}

__global__ __launch_bounds__(256)
void cmax_kernel(const float* __restrict__ rowsum, float* __restrict__ cbuf)
{
    __shared__ float red[256];
    const int t = threadIdx.x;
    float mx = 0.0f;
    for (int k = t; k < NN_; k += 256) mx = fmaxf(mx, rowsum[k]);
    red[t] = mx; __syncthreads();
    for (int off = 128; off > 0; off >>= 1) {
        if (t < off) red[t] = fmaxf(red[t], red[t + off]);
        __syncthreads();
    }
    if (t == 0) cbuf[0] = 2.0f / (1.0f + red[0]);
}

__global__ __launch_bounds__(256)
void initdiag_kernel(float* __restrict__ X, const float* __restrict__ c)
{
    const int idx = blockIdx.x * 256 + threadIdx.x;
    const int p = idx / NN_, q = idx - p * NN_;
    X[idx] = (p == q) ? c[0] : 0.0f;
}

// dec = p0 + p1 (float4)
__global__ __launch_bounds__(256)
void add2_kernel(const float* __restrict__ p0, size_t ps, float* __restrict__ o)
{
    const size_t i = ((size_t)blockIdx.x * 256 + threadIdx.x) * 4;
    const float4 a = *(const float4*)(p0 + i);
    const float4 b = *(const float4*)(p0 + ps + i);
    float4 v;
    v.x = a.x + b.x; v.y = a.y + b.y;
    v.z = a.z + b.z; v.w = a.w + b.w;
    *(float4*)(o + i) = v;
}

extern "C" void kernel_launch(void* const* d_in, const int* in_sizes, int n_in,
                              void* d_out, int out_size, void* d_ws, size_t ws_size,
                              hipStream_t stream)
{
    const float* x = (const float*)d_in[0];   // (2048, 768)
    const float* w = (const float*)d_in[1];   // (3072, 768)

    float* out = (float*)d_out;
    float* z   = out;                          // (2048, 3072)
    float* dec = out + (size_t)BB * MM;        // (2048, 768)

    char* wsb = (char*)d_ws;
    size_t off = 0;
    auto alloc = [&](size_t bytes) -> void* {
        void* p = wsb + off;
        off += (bytes + 255) & ~(size_t)255;
        return p;
    };
    // --- persistent ---
    unsigned short* wnH  = (unsigned short*)alloc((size_t)MM * NN_ * 2);
    unsigned short* wnL  = (unsigned short*)alloc((size_t)MM * NN_ * 2);
    unsigned short* wnTH = (unsigned short*)alloc((size_t)MM * NN_ * 2);
    unsigned short* wnTL = (unsigned short*)alloc((size_t)MM * NN_ * 2);
    float* adotb = (float*)alloc((size_t)BB * MM * 4);
    float* wbuf  = (float*)alloc((size_t)BB * MM * 4);
    unsigned short* y2h = (unsigned short*)alloc((size_t)BB * MM * 2);
    unsigned short* QH  = (unsigned short*)alloc((size_t)NN_ * NN_ * 2);
    unsigned short* QL  = (unsigned short*)alloc((size_t)NN_ * NN_ * 2);
    unsigned short* RTH = (unsigned short*)alloc((size_t)MM * NN_ * 2);
    unsigned short* RTL = (unsigned short*)alloc((size_t)MM * NN_ * 2);
    unsigned short* Thp = (unsigned short*)alloc((size_t)2 * BB * NN_ * 2); // fp16 T partials
    // --- overlay: NS temps (dead after RT) aliased with Tp (decode partials) ---
    const size_t overlay = off;
    float* G  = (float*)alloc((size_t)NN_ * NN_ * 4);
    unsigned short* GH  = (unsigned short*)alloc((size_t)NN_ * NN_ * 2);
    unsigned short* GL  = (unsigned short*)alloc((size_t)NN_ * NN_ * 2);
    float* X0 = (float*)alloc((size_t)NN_ * NN_ * 4);
    float* X1 = (float*)alloc((size_t)NN_ * NN_ * 4);
    float* Yb = (float*)alloc((size_t)NN_ * NN_ * 4);
    unsigned short* YbH = (unsigned short*)alloc((size_t)NN_ * NN_ * 2);
    unsigned short* YbL = (unsigned short*)alloc((size_t)NN_ * NN_ * 2);
    float* rowsum = (float*)alloc(NN_ * 4);
    float* cbuf   = (float*)alloc(256);
    float* Pp = (float*)alloc((size_t)4 * NN_ * NN_ * 4);  // split-K f32 partials
    // Tp (2 x 2048x768 f32 = 12.6 MB) aliases the NS-temp region (~14.2 MB);
    // NS temps dead before first Tp use (RT GEMM f32 scratch / decode partials).
    float* Tp = (float*)(wsb + overlay);
    const size_t TPS = (size_t)BB * NN_;

    (void)hipMemsetAsync(wbuf, 0, (size_t)BB * MM * sizeof(float), stream);

    const dim3 blk(256);
    const dim3 gsk(NN_ / 64, NN_ / 64, 4);
    const int  RED = (NN_ * NN_ / 4) / 256;   // 576

    rownorm_kernel<<<MM, blk, 0, stream>>>(w, wnH, wnL, wnTH, wnTL);

    // adotb = x @ wn^T (M2048 N3072 K768); emit y2_0 = fp16(adotb)
    // BN=128: 32x24 grid, patch 8x12 per XCD
    gemm_big<128,32,24,1,8,12,0,0,1,0><<<768, blk, 0, stream>>>(
        x, nullptr, NN_, 0, wnH, wnL, NN_, adotb, MM, 0, NN_,
        nullptr, nullptr, nullptr, y2h, nullptr, nullptr);

    // G = wn^T wn + I (768x768, K=3072), split-K=4 + reduce(+I, split)
    gemm_sk<1><<<gsk, blk, 0, stream>>>(
        nullptr, wnTH, wnTL, MM, wnTH, wnTL, MM, Pp, MM / 4);
    red_ns<1><<<RED, blk, 0, stream>>>(Pp, nullptr, G, GH, GL);

    rowabs_kernel<<<NN_, blk, 0, stream>>>(G, rowsum);
    cmax_kernel<<<1, blk, 0, stream>>>(rowsum, cbuf);
    initdiag_kernel<<<(NN_ * NN_) / 256, blk, 0, stream>>>(X0, cbuf);

    // Newton-Schulz X <- 2X - XGX, 7 iterations, split-K=4 per GEMM
    float* Xc = X0;
    float* Xn = X1;
    for (int it = 0; it < 7; ++it) {
        gemm_sk<0><<<gsk, blk, 0, stream>>>(
            Xc, nullptr, nullptr, NN_, GH, GL, NN_, Pp, NN_ / 4);
        red_ns<0><<<RED, blk, 0, stream>>>(Pp, nullptr, Yb, YbH, YbL);
        gemm_sk<0><<<gsk, blk, 0, stream>>>(
            Xc, nullptr, nullptr, NN_, YbH, YbL, NN_, Pp, NN_ / 4);
        red_ns<2><<<RED, blk, 0, stream>>>(Pp, Xc, Xn, QH, QL);
        float* t = Xc; Xc = Xn; Xn = t;
    }
    // QH/QL = fp16 split of G^{-1}

    // RT = wn @ Ginv (M3072 N768 K768); emit RTH/RTL (f32 scratch to Tp)
    gemm_big<64,48,12,1,12,6,1,0,2,0><<<576, blk, 0, stream>>>(
        nullptr, wnH, NN_, 0, QH, QL, NN_, Tp, NN_, 0, NN_,
        nullptr, nullptr, nullptr, nullptr, RTH, RTL);

    // ADMM loop: T = y2 @ wn -> fp16 partials Thp (KS=2);
    // w-update (BN=128) sums the fp16 pair in its A-staging (AMODE=4)
    for (int it = 0; it < 20; ++it) {
        gemm_big<64,32,12,2,16,6,1,4,0,0><<<768, blk, 0, stream>>>(
            nullptr, y2h, MM, 0, wnTH, wnTL, MM, nullptr, NN_, TPS, MM / 2,
            nullptr, nullptr, nullptr, Thp, nullptr, nullptr);
        if (it < 19) {
            gemm_big<128,32,24,1,8,12,4,3,0,0><<<768, blk, 0, stream>>>(
                nullptr, Thp, NN_, TPS, RTH, RTL, NN_, nullptr, MM, 0, NN_,
                adotb, wbuf, nullptr, y2h, nullptr, nullptr);
        } else {
            gemm_big<128,32,24,1,8,12,4,3,0,1><<<768, blk, 0, stream>>>(
                nullptr, Thp, NN_, TPS, RTH, RTL, NN_, nullptr, MM, 0, NN_,
                adotb, wbuf, z, nullptr, nullptr, nullptr);
        }
    }

    // decoded = z @ wn (M2048 N768 K3072), KS=2 f32 partials + reduce
    gemm_big<64,32,12,2,16,6,0,0,0,0><<<768, blk, 0, stream>>>(
        z, nullptr, MM, 0, wnTH, wnTL, MM, Tp, NN_, TPS, MM / 2,
        nullptr, nullptr, nullptr, nullptr, nullptr, nullptr);
    add2_kernel<<<(BB * NN_ / 4) / 256, blk, 0, stream>>>(Tp, TPS, dec);
}

// Round 15
// 2166.430 us; speedup vs baseline: 2.4677x; 1.4411x over previous
//
#include <hip/hip_runtime.h>
#include <math.h>

#define BB   2048
#define NN_  768
#define MM   3072
#define LAMBD 0.1f

typedef __attribute__((ext_vector_type(8))) _Float16 half8;
typedef __attribute__((ext_vector_type(4))) float  f32x4;
typedef __attribute__((ext_vector_type(4))) unsigned short us4;

union HB { _Float16 f; unsigned short u; };
struct HL { unsigned short h, l; };

__device__ __forceinline__ unsigned short h_bits(float f) {
    HB b; b.f = (_Float16)f; return b.u;
}
__device__ __forceinline__ HL split2h(float f) {
    HL r;
    HB b; b.f = (_Float16)f;
    r.h = b.u;
    const float fh = (float)b.f;
    HB c; c.f = (_Float16)(f - fh);
    r.l = c.u;
    return r;
}
__device__ __forceinline__ float clampl(float x) {
    return fminf(fmaxf(x, -LAMBD), LAMBD);
}
__device__ __forceinline__ float4 cvt4h(const unsigned short* p) {
    const us4 u = *(const us4*)p;
    HB a, b, c, d;
    a.u = u.x; b.u = u.y; c.u = u.z; d.u = u.w;
    float4 f;
    f.x = (float)a.f; f.y = (float)b.f; f.z = (float)c.f; f.w = (float)d.f;
    return f;
}

// ---------------------------------------------------------------------------
// Split-K small GEMM (768x768 out, fp16 3-term), 64x64 tile, reg-prefetch,
// single LDS buffer + transposed (coalesced) epilogue. Grid: (12, 12, KS).
// (R12-proven form, unchanged.)
// ---------------------------------------------------------------------------
template<int APRE>
__global__ __launch_bounds__(256)
void gemm_sk(const float* __restrict__ A,
             const unsigned short* __restrict__ Ah,
             const unsigned short* __restrict__ Al,
             int lda,
             const unsigned short* __restrict__ Bh,
             const unsigned short* __restrict__ Bl,
             int ldb,
             float* __restrict__ P, int Kper)
{
    __shared__ __align__(16) char smem[20480];
    unsigned short (*AsH)[40] = (unsigned short (*)[40])(smem);
    unsigned short (*AsL)[40] = (unsigned short (*)[40])(smem + 5120);
    unsigned short (*BsH)[40] = (unsigned short (*)[40])(smem + 10240);
    unsigned short (*BsL)[40] = (unsigned short (*)[40])(smem + 15360);

    const int tid  = threadIdx.x;
    const int brow = blockIdx.y * 64;
    const int bcol = blockIdx.x * 64;
    const int koff = blockIdx.z * Kper;
    const int wave = tid >> 6, lane = tid & 63;
    const int wr = wave >> 1, wc = wave & 1;
    const int lrow = lane & 15, kg = lane >> 4;

    const int sk4  = (tid & 7) << 2;

    us4   rAh[2], rAl[2], rBh[2], rBl[2];
    float4 rAf[2];

    auto LOAD = [&](int k0) {
        #pragma unroll
        for (int p = 0; p < 2; ++p) {
            const int row = (p * 256 + tid) >> 3;
            const size_t ga = (size_t)(brow + row) * lda + k0 + sk4;
            const size_t gb = (size_t)(bcol + row) * ldb + k0 + sk4;
            if constexpr (APRE) {
                rAh[p] = *(const us4*)(Ah + ga);
                rAl[p] = *(const us4*)(Al + ga);
            } else {
                rAf[p] = *(const float4*)(A + ga);
            }
            rBh[p] = *(const us4*)(Bh + gb);
            rBl[p] = *(const us4*)(Bl + gb);
        }
    };
    auto STORE = [&]() {
        #pragma unroll
        for (int p = 0; p < 2; ++p) {
            const int row = (p * 256 + tid) >> 3;
            if constexpr (APRE) {
                *(us4*)&AsH[row][sk4] = rAh[p];
                *(us4*)&AsL[row][sk4] = rAl[p];
            } else {
                const HL sx = split2h(rAf[p].x), sy = split2h(rAf[p].y);
                const HL sz = split2h(rAf[p].z), sw = split2h(rAf[p].w);
                us4 h, l;
                h.x = sx.h; l.x = sx.l; h.y = sy.h; l.y = sy.l;
                h.z = sz.h; l.z = sz.l; h.w = sw.h; l.w = sw.l;
                *(us4*)&AsH[row][sk4] = h;
                *(us4*)&AsL[row][sk4] = l;
            }
            *(us4*)&BsH[row][sk4] = rBh[p];
            *(us4*)&BsL[row][sk4] = rBl[p];
        }
    };

    f32x4 acc[2][2];
    #pragma unroll
    for (int m = 0; m < 2; ++m)
        #pragma unroll
        for (int n = 0; n < 2; ++n)
            #pragma unroll
            for (int q = 0; q < 4; ++q) acc[m][n][q] = 0.0f;

    const int NK = Kper / 32;
    LOAD(koff);
    STORE();
    __syncthreads();

    for (int ki = 0; ki < NK; ++ki) {
        if (ki + 1 < NK) LOAD(koff + (ki + 1) * 32);

        half8 ahi[2], alo[2], bhi[2], blo[2];
        #pragma unroll
        for (int m = 0; m < 2; ++m) {
            const int r = wr * 32 + m * 16 + lrow;
            ahi[m] = *(const half8*)&AsH[r][kg * 8];
            alo[m] = *(const half8*)&AsL[r][kg * 8];
        }
        #pragma unroll
        for (int n = 0; n < 2; ++n) {
            const int c = wc * 32 + n * 16 + lrow;
            bhi[n] = *(const half8*)&BsH[c][kg * 8];
            blo[n] = *(const half8*)&BsL[c][kg * 8];
        }
        #pragma unroll
        for (int m = 0; m < 2; ++m)
            #pragma unroll
            for (int n = 0; n < 2; ++n) {
                acc[m][n] = __builtin_amdgcn_mfma_f32_16x16x32_f16(ahi[m], bhi[n], acc[m][n], 0, 0, 0);
                acc[m][n] = __builtin_amdgcn_mfma_f32_16x16x32_f16(ahi[m], blo[n], acc[m][n], 0, 0, 0);
                acc[m][n] = __builtin_amdgcn_mfma_f32_16x16x32_f16(alo[m], bhi[n], acc[m][n], 0, 0, 0);
            }
        __syncthreads();
        if (ki + 1 < NK) { STORE(); __syncthreads(); }
    }

    // transposed epilogue: acc -> LDS [64][65] -> coalesced float4 rows
    float* eb = (float*)smem;
    #pragma unroll
    for (int m = 0; m < 2; ++m)
        #pragma unroll
        for (int n = 0; n < 2; ++n)
            #pragma unroll
            for (int r = 0; r < 4; ++r)
                eb[(wr * 32 + m * 16 + kg * 4 + r) * 65 + wc * 32 + n * 16 + lrow] = acc[m][n][r];
    __syncthreads();
    float* Pk = P + (size_t)blockIdx.z * NN_ * NN_;
    #pragma unroll
    for (int j = 0; j < 4; ++j) {
        const int row = wave * 16 + j * 4 + (lane >> 4);
        const int col = (lane & 15) * 4;
        const float4 v = *(const float4*)&eb[row * 65 + col];
        *(float4*)(Pk + (size_t)(brow + row) * NN_ + bcol + col) = v;
    }
}

// Reduce 4 split-K partials with epilogue. MODE: 0 plain, 1 +I, 2 2*E1-sum.
template<int MODE>
__global__ __launch_bounds__(256)
void red_ns(const float* __restrict__ P,
            const float* __restrict__ E1,
            float* __restrict__ C,
            unsigned short* __restrict__ Ch,
            unsigned short* __restrict__ Cl)
{
    const size_t i4 = ((size_t)blockIdx.x * 256 + threadIdx.x) * 4;
    const size_t sz = (size_t)NN_ * NN_;
    float4 s = *(const float4*)(P + i4);
    const float4 s1 = *(const float4*)(P + sz + i4);
    const float4 s2 = *(const float4*)(P + 2 * sz + i4);
    const float4 s3 = *(const float4*)(P + 3 * sz + i4);
    s.x = (s.x + s1.x) + (s2.x + s3.x);
    s.y = (s.y + s1.y) + (s2.y + s3.y);
    s.z = (s.z + s1.z) + (s2.z + s3.z);
    s.w = (s.w + s1.w) + (s2.w + s3.w);
    float v[4] = {s.x, s.y, s.z, s.w};
    if constexpr (MODE == 1) {
        const int row = (int)(i4 / NN_);
        const int col = (int)(i4 - (size_t)row * NN_);
        #pragma unroll
        for (int j = 0; j < 4; ++j) if (row == col + j) v[j] += 1.0f;
    }
    if constexpr (MODE == 2) {
        const float4 e = *(const float4*)(E1 + i4);
        v[0] = 2.0f * e.x - v[0]; v[1] = 2.0f * e.y - v[1];
        v[2] = 2.0f * e.z - v[2]; v[3] = 2.0f * e.w - v[3];
    }
    float4 o; o.x = v[0]; o.y = v[1]; o.z = v[2]; o.w = v[3];
    *(float4*)(C + i4) = o;
    us4 h, l;
    const HL a = split2h(v[0]), b = split2h(v[1]);
    const HL c = split2h(v[2]), d = split2h(v[3]);
    h.x = a.h; l.x = a.l; h.y = b.h; l.y = b.l;
    h.z = c.h; l.z = c.l; h.w = d.h; l.w = d.l;
    *(us4*)(Ch + i4) = h;
    *(us4*)(Cl + i4) = l;
}

// ---------------------------------------------------------------------------
// Big fp16 2-term GEMM: 64x64 tile, 4 waves (32x32), BK=32, reg-prefetch,
// single LDS buffer + transposed (coalesced) epilogue. (R12 structure.)
// AMODE: 0 f32 A -> cvt; 1 pre-cvt fp16 (Ah); 4 fp16 pair Ah/Ah+psz summed.
// EPI: 0 C=acc f32 (+EMIT); 3 ADMM w-update on fp16 h/l state streams;
//      4 fp16 partial -> Y2[cks*ks+gi].
// EMIT: 0 none, 1 Y2=fp16(acc), 2 EH/EL=split(acc), 3 Y2+EH/EL, NO C write.
// Grid: flat NBM*NBN*KS; per-XCD 2D patch PM x PN for L2 reuse.
// ---------------------------------------------------------------------------
template<int NBM, int NBN, int KS, int PM, int PN, int AMODE, int EPI, int EMIT, int LASTZ>
__global__ __launch_bounds__(256)
void gemm_big(const float* __restrict__ A,
              const unsigned short* __restrict__ Ah,
              int lda, size_t psz,
              const unsigned short* __restrict__ Bh,
              const unsigned short* __restrict__ Bl,
              int ldb,
              float* __restrict__ C, int ldc, size_t cks, int Kper,
              const unsigned short* __restrict__ F1H,
              const unsigned short* __restrict__ F1L,
              unsigned short* __restrict__ WH,
              unsigned short* __restrict__ WL,
              float* __restrict__ OutZ,
              unsigned short* __restrict__ Y2,
              unsigned short* __restrict__ EH,
              unsigned short* __restrict__ EL)
{
    static_assert(NBM % PM == 0 && NBN % PN == 0, "patch divides grid");
    constexpr int XM = NBM / PM, XN = NBN / PN;
    static_assert(XM * XN * KS == 8, "patches x KS must equal 8 XCDs");
    static_assert(PM * PN == (NBM * NBN * KS) / 8, "slot count");

    __shared__ __align__(16) char smem[16640];
    unsigned short (*AsH)[40] = (unsigned short (*)[40])(smem);
    unsigned short (*BsH)[40] = (unsigned short (*)[40])(smem + 5120);
    unsigned short (*BsL)[40] = (unsigned short (*)[40])(smem + 10240);

    const int bid  = blockIdx.x;
    const int xcd  = bid & 7;
    const int slot = bid >> 3;
    const int ks   = xcd % KS;
    const int rest = xcd / KS;
    const int xn   = rest % XN;
    const int xm   = rest / XN;
    const int m_   = xm * PM + slot / PN;
    const int n_   = xn * PN + slot % PN;
    const int brow = m_ * 64;
    const int bcol = n_ * 64;
    const int koff = ks * Kper;

    const int tid  = threadIdx.x;
    const int wave = tid >> 6, lane = tid & 63;
    const int wr = wave >> 1, wc = wave & 1;
    const int lrow = lane & 15, kg = lane >> 4;

    const int srow = tid >> 2, sk8 = (tid & 3) << 3;

    uint4  pA0, pA1, pB0, pB1;
    float4 pF[2];

    auto LOAD = [&](int k0) {
        const size_t ga = (size_t)(brow + srow) * lda + k0 + sk8;
        if constexpr (AMODE == 1) {
            pA0 = *(const uint4*)(Ah + ga);
        } else if constexpr (AMODE == 4) {
            pA0 = *(const uint4*)(Ah + ga);
            pA1 = *(const uint4*)(Ah + ga + psz);
        } else {
            pF[0] = *(const float4*)(A + ga);
            pF[1] = *(const float4*)(A + ga + 4);
        }
        const size_t gb = (size_t)(bcol + srow) * ldb + k0 + sk8;
        pB0 = *(const uint4*)(Bh + gb);
        pB1 = *(const uint4*)(Bl + gb);
    };
    auto STORE = [&]() {
        if constexpr (AMODE == 1) {
            *(uint4*)&AsH[srow][sk8] = pA0;
        } else if constexpr (AMODE == 4) {
            half8 h0 = *(half8*)&pA0;
            half8 h1 = *(half8*)&pA1;
            half8 hs = h0 + h1;
            *(half8*)&AsH[srow][sk8] = hs;
        } else {
            float va[8];
            va[0] = pF[0].x; va[1] = pF[0].y; va[2] = pF[0].z; va[3] = pF[0].w;
            va[4] = pF[1].x; va[5] = pF[1].y; va[6] = pF[1].z; va[7] = pF[1].w;
            half8 h0;
            #pragma unroll
            for (int j = 0; j < 8; ++j) h0[j] = (_Float16)va[j];
            *(half8*)&AsH[srow][sk8] = h0;
        }
        *(uint4*)&BsH[srow][sk8] = pB0;
        *(uint4*)&BsL[srow][sk8] = pB1;
    };

    f32x4 acc[2][2];
    #pragma unroll
    for (int m = 0; m < 2; ++m)
        #pragma unroll
        for (int n = 0; n < 2; ++n)
            #pragma unroll
            for (int q = 0; q < 4; ++q) acc[m][n][q] = 0.0f;

    const int NK = Kper / 32;
    LOAD(koff);
    STORE();
    __syncthreads();

    for (int ki = 0; ki < NK; ++ki) {
        if (ki + 1 < NK) LOAD(koff + (ki + 1) * 32);

        half8 a[2], bh[2], bl[2];
        #pragma unroll
        for (int m = 0; m < 2; ++m)
            a[m] = *(const half8*)&AsH[wr * 32 + m * 16 + lrow][kg * 8];
        #pragma unroll
        for (int n = 0; n < 2; ++n) {
            const int c = wc * 32 + n * 16 + lrow;
            bh[n] = *(const half8*)&BsH[c][kg * 8];
            bl[n] = *(const half8*)&BsL[c][kg * 8];
        }
        #pragma unroll
        for (int m = 0; m < 2; ++m)
            #pragma unroll
            for (int n = 0; n < 2; ++n) {
                acc[m][n] = __builtin_amdgcn_mfma_f32_16x16x32_f16(a[m], bh[n], acc[m][n], 0, 0, 0);
                acc[m][n] = __builtin_amdgcn_mfma_f32_16x16x32_f16(a[m], bl[n], acc[m][n], 0, 0, 0);
            }
        __syncthreads();
        if (ki + 1 < NK) { STORE(); __syncthreads(); }
    }

    // ---- transposed epilogue: acc -> LDS [64][65] -> whole-row float4 I/O ----
    float* eb = (float*)smem;
    #pragma unroll
    for (int m = 0; m < 2; ++m)
        #pragma unroll
        for (int n = 0; n < 2; ++n)
            #pragma unroll
            for (int r = 0; r < 4; ++r)
                eb[(wr * 32 + m * 16 + kg * 4 + r) * 65 + wc * 32 + n * 16 + lrow] = acc[m][n][r];
    __syncthreads();

    #pragma unroll
    for (int j = 0; j < 4; ++j) {
        const int row = wave * 16 + j * 4 + (lane >> 4);
        const int col = (lane & 15) * 4;
        const float4 v = *(const float4*)&eb[row * 65 + col];
        const size_t gi = (size_t)(brow + row) * ldc + bcol + col;
        if constexpr (EPI == 0) {
            if constexpr (EMIT != 3)
                *(float4*)(C + cks * ks + gi) = v;
            if constexpr (EMIT == 1) {
                us4 h;
                h.x = h_bits(v.x); h.y = h_bits(v.y);
                h.z = h_bits(v.z); h.w = h_bits(v.w);
                *(us4*)(Y2 + gi) = h;
            }
            if constexpr (EMIT == 2 || EMIT == 3) {
                const HL a = split2h(v.x), b = split2h(v.y);
                const HL c2 = split2h(v.z), d = split2h(v.w);
                us4 h, l;
                h.x = a.h; l.x = a.l; h.y = b.h; l.y = b.l;
                h.z = c2.h; l.z = c2.l; h.w = d.h; l.w = d.l;
                *(us4*)(EH + gi) = h;
                *(us4*)(EL + gi) = l;
                if constexpr (EMIT == 3) {
                    us4 y;
                    y.x = h_bits(v.x); y.y = h_bits(v.y);
                    y.z = h_bits(v.z); y.w = h_bits(v.w);
                    *(us4*)(Y2 + gi) = y;
                }
            }
        } else if constexpr (EPI == 4) {   // fp16 partial write (T-GEMM)
            us4 h;
            h.x = h_bits(v.x); h.y = h_bits(v.y);
            h.z = h_bits(v.z); h.w = h_bits(v.w);
            *(us4*)(Y2 + cks * ks + gi) = h;
        } else { // EPI == 3: ADMM w-update on fp16 h/l state streams
            const float4 f1h = cvt4h(F1H + gi);
            const float4 f1l = cvt4h(F1L + gi);
            const float4 wh_ = cvt4h(WH + gi);
            const float4 wl_ = cvt4h(WL + gi);
            const float f1v[4] = {f1h.x + f1l.x, f1h.y + f1l.y,
                                  f1h.z + f1l.z, f1h.w + f1l.w};
            const float wwv[4] = {wh_.x + wl_.x, wh_.y + wl_.y,
                                  wh_.z + wl_.z, wh_.w + wl_.w};
            const float vv[4] = {v.x, v.y, v.z, v.w};
            float wn[4];
            #pragma unroll
            for (int q = 0; q < 4; ++q)
                wn[q] = f1v[q] + wwv[q] - clampl(wwv[q]) - vv[q];
            if constexpr (LASTZ) {
                float4 o;
                o.x = wn[0] - clampl(wn[0]); o.y = wn[1] - clampl(wn[1]);
                o.z = wn[2] - clampl(wn[2]); o.w = wn[3] - clampl(wn[3]);
                *(float4*)(OutZ + gi) = o;
            } else {
                us4 hh, ll, y;
                #pragma unroll
                for (int q = 0; q < 4; ++q) {
                    const HL s = split2h(wn[q]);
                    ((unsigned short*)&hh)[q] = s.h;
                    ((unsigned short*)&ll)[q] = s.l;
                    ((unsigned short*)&y)[q]  = h_bits(f1v[q] + wn[q] - 2.0f * clampl(wn[q]));
                }
                *(us4*)(WH + gi) = hh;
                *(us4*)(WL + gi) = ll;
                *(us4*)(Y2 + gi) = y;
            }
        }
    }
}

// Normalize rows of weight (3072x768); emit fp16 h/l of wn and wn^T.
__global__ __launch_bounds__(256)
void rownorm_kernel(const float* __restrict__ W,
                    unsigned short* __restrict__ wnH, unsigned short* __restrict__ wnL,
                    unsigned short* __restrict__ wnTH, unsigned short* __restrict__ wnTL)
{
    __shared__ float red[256];
    const int row = blockIdx.x;
    const int t = threadIdx.x;
    const float* wr = W + (size_t)row * NN_;
    float s = 0.0f;
    for (int k = t; k < NN_; k += 256) { const float w = wr[k]; s += w * w; }
    red[t] = s; __syncthreads();
    for (int off = 128; off > 0; off >>= 1) {
        if (t < off) red[t] += red[t + off];
        __syncthreads();
    }
    const float rn = 1.0f / sqrtf(red[0]);
    for (int k = t; k < NN_; k += 256) {
        const float v = wr[k] * rn;
        const HL s2 = split2h(v);
        wnH[(size_t)row * NN_ + k] = s2.h;
        wnL[(size_t)row * NN_ + k] = s2.l;
        wnTH[(size_t)k * MM + row] = s2.h;
        wnTL[(size_t)k * MM + row] = s2.l;
    }
}

__global__ __launch_bounds__(256)
void rowabs_kernel(const float* __restrict__ G, float* __restrict__ rowsum)
{
    __shared__ float red[256];
    const int row = blockIdx.x;
    const int t = threadIdx.x;
    const float* gr = G + (size_t)row * NN_;
    float s = 0.0f;
    for (int k = t; k < NN_; k += 256) s += fabsf(gr[k]);
    red[t] = s; __syncthreads();
    for (int off = 128; off > 0; off >>= 1) {
        if (t < off) red[t] += red[t + off];
        __syncthreads();
    }
    if (t == 0) rowsum[row] = red[0];
}

__global__ __launch_bounds__(256)
void cmax_kernel(const float* __restrict__ rowsum, float* __restrict__ cbuf)
{
    __shared__ float red[256];
    const int t = threadIdx.x;
    float mx = 0.0f;
    for (int k = t; k < NN_; k += 256) mx = fmaxf(mx, rowsum[k]);
    red[t] = mx; __syncthreads();
    for (int off = 128; off > 0; off >>= 1) {
        if (t < off) red[t] = fmaxf(red[t], red[t + off]);
        __syncthreads();
    }
    if (t == 0) cbuf[0] = 2.0f / (1.0f + red[0]);
}

__global__ __launch_bounds__(256)
void initdiag_kernel(float* __restrict__ X, const float* __restrict__ c)
{
    const int idx = blockIdx.x * 256 + threadIdx.x;
    const int p = idx / NN_, q = idx - p * NN_;
    X[idx] = (p == q) ? c[0] : 0.0f;
}

// dec = p0 + p1 (float4)
__global__ __launch_bounds__(256)
void add2_kernel(const float* __restrict__ p0, size_t ps, float* __restrict__ o)
{
    const size_t i = ((size_t)blockIdx.x * 256 + threadIdx.x) * 4;
    const float4 a = *(const float4*)(p0 + i);
    const float4 b = *(const float4*)(p0 + ps + i);
    float4 v;
    v.x = a.x + b.x; v.y = a.y + b.y;
    v.z = a.z + b.z; v.w = a.w + b.w;
    *(float4*)(o + i) = v;
}

extern "C" void kernel_launch(void* const* d_in, const int* in_sizes, int n_in,
                              void* d_out, int out_size, void* d_ws, size_t ws_size,
                              hipStream_t stream)
{
    const float* x = (const float*)d_in[0];   // (2048, 768)
    const float* w = (const float*)d_in[1];   // (3072, 768)

    float* out = (float*)d_out;
    float* z   = out;                          // (2048, 3072)
    float* dec = out + (size_t)BB * MM;        // (2048, 768)

    char* wsb = (char*)d_ws;
    size_t off = 0;
    auto alloc = [&](size_t bytes) -> void* {
        void* p = wsb + off;
        off += (bytes + 255) & ~(size_t)255;
        return p;
    };
    // --- persistent ---
    unsigned short* wnH  = (unsigned short*)alloc((size_t)MM * NN_ * 2);
    unsigned short* wnL  = (unsigned short*)alloc((size_t)MM * NN_ * 2);
    unsigned short* wnTH = (unsigned short*)alloc((size_t)MM * NN_ * 2);
    unsigned short* wnTL = (unsigned short*)alloc((size_t)MM * NN_ * 2);
    unsigned short* adH  = (unsigned short*)alloc((size_t)BB * MM * 2);  // adotb hi
    unsigned short* adL  = (unsigned short*)alloc((size_t)BB * MM * 2);  // adotb lo
    unsigned short* wbH  = (unsigned short*)alloc((size_t)BB * MM * 2);  // w-state hi
    unsigned short* wbL  = (unsigned short*)alloc((size_t)BB * MM * 2);  // w-state lo
    unsigned short* y2h = (unsigned short*)alloc((size_t)BB * MM * 2);
    unsigned short* QH  = (unsigned short*)alloc((size_t)NN_ * NN_ * 2);
    unsigned short* QL  = (unsigned short*)alloc((size_t)NN_ * NN_ * 2);
    unsigned short* RTH = (unsigned short*)alloc((size_t)MM * NN_ * 2);
    unsigned short* RTL = (unsigned short*)alloc((size_t)MM * NN_ * 2);
    unsigned short* Thp = (unsigned short*)alloc((size_t)2 * BB * NN_ * 2); // fp16 T partials
    // --- overlay: NS temps (dead after RT) aliased with Tp (decode partials) ---
    const size_t overlay = off;
    float* G  = (float*)alloc((size_t)NN_ * NN_ * 4);
    unsigned short* GH  = (unsigned short*)alloc((size_t)NN_ * NN_ * 2);
    unsigned short* GL  = (unsigned short*)alloc((size_t)NN_ * NN_ * 2);
    float* X0 = (float*)alloc((size_t)NN_ * NN_ * 4);
    float* X1 = (float*)alloc((size_t)NN_ * NN_ * 4);
    float* Yb = (float*)alloc((size_t)NN_ * NN_ * 4);
    unsigned short* YbH = (unsigned short*)alloc((size_t)NN_ * NN_ * 2);
    unsigned short* YbL = (unsigned short*)alloc((size_t)NN_ * NN_ * 2);
    float* rowsum = (float*)alloc(NN_ * 4);
    float* cbuf   = (float*)alloc(256);
    float* Pp = (float*)alloc((size_t)4 * NN_ * NN_ * 4);  // split-K f32 partials
    // Tp (2 x 2048x768 f32 = 12.6 MB) aliases the NS-temp region (~14.2 MB);
    // NS temps dead before first Tp use (RT GEMM f32 scratch / decode partials).
    float* Tp = (float*)(wsb + overlay);
    const size_t TPS = (size_t)BB * NN_;

    (void)hipMemsetAsync(wbH, 0, (size_t)BB * MM * sizeof(unsigned short), stream);
    (void)hipMemsetAsync(wbL, 0, (size_t)BB * MM * sizeof(unsigned short), stream);

    const dim3 blk(256);
    const dim3 gsk(NN_ / 64, NN_ / 64, 4);
    const int  RED = (NN_ * NN_ / 4) / 256;   // 576

    rownorm_kernel<<<MM, blk, 0, stream>>>(w, wnH, wnL, wnTH, wnTL);

    // adotb = x @ wn^T (M2048 N3072 K768); emit y2_0 + adotb h/l (no f32 C)
    gemm_big<32,48,1,8,24,0,0,3,0><<<1536, blk, 0, stream>>>(
        x, nullptr, NN_, 0, wnH, wnL, NN_, nullptr, MM, 0, NN_,
        nullptr, nullptr, nullptr, nullptr, nullptr, y2h, adH, adL);

    // G = wn^T wn + I (768x768, K=3072), split-K=4 + reduce(+I, split)
    gemm_sk<1><<<gsk, blk, 0, stream>>>(
        nullptr, wnTH, wnTL, MM, wnTH, wnTL, MM, Pp, MM / 4);
    red_ns<1><<<RED, blk, 0, stream>>>(Pp, nullptr, G, GH, GL);

    rowabs_kernel<<<NN_, blk, 0, stream>>>(G, rowsum);
    cmax_kernel<<<1, blk, 0, stream>>>(rowsum, cbuf);
    initdiag_kernel<<<(NN_ * NN_) / 256, blk, 0, stream>>>(X0, cbuf);

    // Newton-Schulz X <- 2X - XGX, 7 iterations, split-K=4 per GEMM
    float* Xc = X0;
    float* Xn = X1;
    for (int it = 0; it < 7; ++it) {
        gemm_sk<0><<<gsk, blk, 0, stream>>>(
            Xc, nullptr, nullptr, NN_, GH, GL, NN_, Pp, NN_ / 4);
        red_ns<0><<<RED, blk, 0, stream>>>(Pp, nullptr, Yb, YbH, YbL);
        gemm_sk<0><<<gsk, blk, 0, stream>>>(
            Xc, nullptr, nullptr, NN_, YbH, YbL, NN_, Pp, NN_ / 4);
        red_ns<2><<<RED, blk, 0, stream>>>(Pp, Xc, Xn, QH, QL);
        float* t = Xc; Xc = Xn; Xn = t;
    }
    // QH/QL = fp16 split of G^{-1}

    // RT = wn @ Ginv (M3072 N768 K768); emit RTH/RTL (f32 scratch to Tp)
    gemm_big<48,12,1,12,6,1,0,2,0><<<576, blk, 0, stream>>>(
        nullptr, wnH, NN_, 0, QH, QL, NN_, Tp, NN_, 0, NN_,
        nullptr, nullptr, nullptr, nullptr, nullptr, nullptr, RTH, RTL);

    // ADMM loop: T = y2 @ wn -> fp16 partials Thp (KS=2);
    // w-update sums the fp16 pair in-register (AMODE=4), state in fp16 h/l
    for (int it = 0; it < 20; ++it) {
        gemm_big<32,12,2,16,6,1,4,0,0><<<768, blk, 0, stream>>>(
            nullptr, y2h, MM, 0, wnTH, wnTL, MM, nullptr, NN_, TPS, MM / 2,
            nullptr, nullptr, nullptr, nullptr, nullptr, Thp, nullptr, nullptr);
        if (it < 19) {
            gemm_big<32,48,1,8,24,4,3,0,0><<<1536, blk, 0, stream>>>(
                nullptr, Thp, NN_, TPS, RTH, RTL, NN_, nullptr, MM, 0, NN_,
                adH, adL, wbH, wbL, nullptr, y2h, nullptr, nullptr);
        } else {
            gemm_big<32,48,1,8,24,4,3,0,1><<<1536, blk, 0, stream>>>(
                nullptr, Thp, NN_, TPS, RTH, RTL, NN_, nullptr, MM, 0, NN_,
                adH, adL, wbH, wbL, z, y2h, nullptr, nullptr);
        }
    }

    // decoded = z @ wn (M2048 N768 K3072), KS=2 f32 partials + reduce
    gemm_big<32,12,2,16,6,0,0,0,0><<<768, blk, 0, stream>>>(
        z, nullptr, MM, 0, wnTH, wnTL, MM, Tp, NN_, TPS, MM / 2,
        nullptr, nullptr, nullptr, nullptr, nullptr, nullptr, nullptr, nullptr);
    add2_kernel<<<(BB * NN_ / 4) / 256, blk, 0, stream>>>(Tp, TPS, dec);
}

// Round 16
// 1745.552 us; speedup vs baseline: 3.0627x; 1.2411x over previous
//
#include <hip/hip_runtime.h>
#include <math.h>

#define BB   2048
#define NN_  768
#define MM   3072
#define LAMBD 0.1f

typedef __attribute__((ext_vector_type(8))) _Float16 half8;
typedef __attribute__((ext_vector_type(4))) float  f32x4;
typedef __attribute__((ext_vector_type(4))) unsigned short us4;

union HB { _Float16 f; unsigned short u; };
struct HL { unsigned short h, l; };

__device__ __forceinline__ unsigned short h_bits(float f) {
    HB b; b.f = (_Float16)f; return b.u;
}
__device__ __forceinline__ HL split2h(float f) {
    HL r;
    HB b; b.f = (_Float16)f;
    r.h = b.u;
    const float fh = (float)b.f;
    HB c; c.f = (_Float16)(f - fh);
    r.l = c.u;
    return r;
}
__device__ __forceinline__ float clampl(float x) {
    return fminf(fmaxf(x, -LAMBD), LAMBD);
}

// ---------------------------------------------------------------------------
// Split-K small GEMM (768x768 out, fp16 3-term), 64x64 tile, reg-prefetch,
// single LDS buffer + transposed (coalesced) epilogue. Grid: (12, 12, KS).
// (R12-proven form, unchanged.)
// ---------------------------------------------------------------------------
template<int APRE>
__global__ __launch_bounds__(256)
void gemm_sk(const float* __restrict__ A,
             const unsigned short* __restrict__ Ah,
             const unsigned short* __restrict__ Al,
             int lda,
             const unsigned short* __restrict__ Bh,
             const unsigned short* __restrict__ Bl,
             int ldb,
             float* __restrict__ P, int Kper)
{
    __shared__ __align__(16) char smem[20480];
    unsigned short (*AsH)[40] = (unsigned short (*)[40])(smem);
    unsigned short (*AsL)[40] = (unsigned short (*)[40])(smem + 5120);
    unsigned short (*BsH)[40] = (unsigned short (*)[40])(smem + 10240);
    unsigned short (*BsL)[40] = (unsigned short (*)[40])(smem + 15360);

    const int tid  = threadIdx.x;
    const int brow = blockIdx.y * 64;
    const int bcol = blockIdx.x * 64;
    const int koff = blockIdx.z * Kper;
    const int wave = tid >> 6, lane = tid & 63;
    const int wr = wave >> 1, wc = wave & 1;
    const int lrow = lane & 15, kg = lane >> 4;

    const int sk4  = (tid & 7) << 2;

    us4   rAh[2], rAl[2], rBh[2], rBl[2];
    float4 rAf[2];

    auto LOAD = [&](int k0) {
        #pragma unroll
        for (int p = 0; p < 2; ++p) {
            const int row = (p * 256 + tid) >> 3;
            const size_t ga = (size_t)(brow + row) * lda + k0 + sk4;
            const size_t gb = (size_t)(bcol + row) * ldb + k0 + sk4;
            if constexpr (APRE) {
                rAh[p] = *(const us4*)(Ah + ga);
                rAl[p] = *(const us4*)(Al + ga);
            } else {
                rAf[p] = *(const float4*)(A + ga);
            }
            rBh[p] = *(const us4*)(Bh + gb);
            rBl[p] = *(const us4*)(Bl + gb);
        }
    };
    auto STORE = [&]() {
        #pragma unroll
        for (int p = 0; p < 2; ++p) {
            const int row = (p * 256 + tid) >> 3;
            if constexpr (APRE) {
                *(us4*)&AsH[row][sk4] = rAh[p];
                *(us4*)&AsL[row][sk4] = rAl[p];
            } else {
                const HL sx = split2h(rAf[p].x), sy = split2h(rAf[p].y);
                const HL sz = split2h(rAf[p].z), sw = split2h(rAf[p].w);
                us4 h, l;
                h.x = sx.h; l.x = sx.l; h.y = sy.h; l.y = sy.l;
                h.z = sz.h; l.z = sz.l; h.w = sw.h; l.w = sw.l;
                *(us4*)&AsH[row][sk4] = h;
                *(us4*)&AsL[row][sk4] = l;
            }
            *(us4*)&BsH[row][sk4] = rBh[p];
            *(us4*)&BsL[row][sk4] = rBl[p];
        }
    };

    f32x4 acc[2][2];
    #pragma unroll
    for (int m = 0; m < 2; ++m)
        #pragma unroll
        for (int n = 0; n < 2; ++n)
            #pragma unroll
            for (int q = 0; q < 4; ++q) acc[m][n][q] = 0.0f;

    const int NK = Kper / 32;
    LOAD(koff);
    STORE();
    __syncthreads();

    for (int ki = 0; ki < NK; ++ki) {
        if (ki + 1 < NK) LOAD(koff + (ki + 1) * 32);

        half8 ahi[2], alo[2], bhi[2], blo[2];
        #pragma unroll
        for (int m = 0; m < 2; ++m) {
            const int r = wr * 32 + m * 16 + lrow;
            ahi[m] = *(const half8*)&AsH[r][kg * 8];
            alo[m] = *(const half8*)&AsL[r][kg * 8];
        }
        #pragma unroll
        for (int n = 0; n < 2; ++n) {
            const int c = wc * 32 + n * 16 + lrow;
            bhi[n] = *(const half8*)&BsH[c][kg * 8];
            blo[n] = *(const half8*)&BsL[c][kg * 8];
        }
        #pragma unroll
        for (int m = 0; m < 2; ++m)
            #pragma unroll
            for (int n = 0; n < 2; ++n) {
                acc[m][n] = __builtin_amdgcn_mfma_f32_16x16x32_f16(ahi[m], bhi[n], acc[m][n], 0, 0, 0);
                acc[m][n] = __builtin_amdgcn_mfma_f32_16x16x32_f16(ahi[m], blo[n], acc[m][n], 0, 0, 0);
                acc[m][n] = __builtin_amdgcn_mfma_f32_16x16x32_f16(alo[m], bhi[n], acc[m][n], 0, 0, 0);
            }
        __syncthreads();
        if (ki + 1 < NK) { STORE(); __syncthreads(); }
    }

    // transposed epilogue: acc -> LDS [64][65] -> coalesced float4 rows
    float* eb = (float*)smem;
    #pragma unroll
    for (int m = 0; m < 2; ++m)
        #pragma unroll
        for (int n = 0; n < 2; ++n)
            #pragma unroll
            for (int r = 0; r < 4; ++r)
                eb[(wr * 32 + m * 16 + kg * 4 + r) * 65 + wc * 32 + n * 16 + lrow] = acc[m][n][r];
    __syncthreads();
    float* Pk = P + (size_t)blockIdx.z * NN_ * NN_;
    #pragma unroll
    for (int j = 0; j < 4; ++j) {
        const int row = wave * 16 + j * 4 + (lane >> 4);
        const int col = (lane & 15) * 4;
        const float4 v = *(const float4*)&eb[row * 65 + col];
        *(float4*)(Pk + (size_t)(brow + row) * NN_ + bcol + col) = v;
    }
}

// Reduce 4 split-K partials with epilogue. MODE: 0 plain, 1 +I, 2 2*E1-sum.
template<int MODE>
__global__ __launch_bounds__(256)
void red_ns(const float* __restrict__ P,
            const float* __restrict__ E1,
            float* __restrict__ C,
            unsigned short* __restrict__ Ch,
            unsigned short* __restrict__ Cl)
{
    const size_t i4 = ((size_t)blockIdx.x * 256 + threadIdx.x) * 4;
    const size_t sz = (size_t)NN_ * NN_;
    float4 s = *(const float4*)(P + i4);
    const float4 s1 = *(const float4*)(P + sz + i4);
    const float4 s2 = *(const float4*)(P + 2 * sz + i4);
    const float4 s3 = *(const float4*)(P + 3 * sz + i4);
    s.x = (s.x + s1.x) + (s2.x + s3.x);
    s.y = (s.y + s1.y) + (s2.y + s3.y);
    s.z = (s.z + s1.z) + (s2.z + s3.z);
    s.w = (s.w + s1.w) + (s2.w + s3.w);
    float v[4] = {s.x, s.y, s.z, s.w};
    if constexpr (MODE == 1) {
        const int row = (int)(i4 / NN_);
        const int col = (int)(i4 - (size_t)row * NN_);
        #pragma unroll
        for (int j = 0; j < 4; ++j) if (row == col + j) v[j] += 1.0f;
    }
    if constexpr (MODE == 2) {
        const float4 e = *(const float4*)(E1 + i4);
        v[0] = 2.0f * e.x - v[0]; v[1] = 2.0f * e.y - v[1];
        v[2] = 2.0f * e.z - v[2]; v[3] = 2.0f * e.w - v[3];
    }
    float4 o; o.x = v[0]; o.y = v[1]; o.z = v[2]; o.w = v[3];
    *(float4*)(C + i4) = o;
    us4 h, l;
    const HL a = split2h(v[0]), b = split2h(v[1]);
    const HL c = split2h(v[2]), d = split2h(v[3]);
    h.x = a.h; l.x = a.l; h.y = b.h; l.y = b.l;
    h.z = c.h; l.z = c.l; h.w = d.h; l.w = d.l;
    *(us4*)(Ch + i4) = h;
    *(us4*)(Cl + i4) = l;
}

// ---------------------------------------------------------------------------
// Big fp16 GEMM: 64x64 tile, 4 waves (32x32), BK=32, reg-prefetch,
// single LDS buffer + transposed (coalesced) epilogue. (R12 structure.)
// AMODE: 0 f32 A -> cvt; 1 pre-cvt fp16 (Ah); 4 fp16 pair Ah/Ah+psz summed.
// BS: 1 = B single fp16 (Bh only, 1 MFMA per mn); 0 = B 2-term h/l.
// EPI: 0 C=acc f32 (+EMIT); 3 ADMM w-update; 4 fp16 partial -> Y2[cks*ks+gi].
// EMIT: 0 none, 1 Y2=fp16(acc), 2 EH/EL = split fp16(acc).
// Grid: flat NBM*NBN*KS; per-XCD 2D patch PM x PN for L2 reuse.
// ---------------------------------------------------------------------------
template<int NBM, int NBN, int KS, int PM, int PN, int AMODE, int BS, int EPI, int EMIT, int LASTZ>
__global__ __launch_bounds__(256)
void gemm_big(const float* __restrict__ A,
              const unsigned short* __restrict__ Ah,
              int lda, size_t psz,
              const unsigned short* __restrict__ Bh,
              const unsigned short* __restrict__ Bl,
              int ldb,
              float* __restrict__ C, int ldc, size_t cks, int Kper,
              const float* __restrict__ F1,
              float* __restrict__ Wio,
              float* __restrict__ OutZ,
              unsigned short* __restrict__ Y2,
              unsigned short* __restrict__ EH,
              unsigned short* __restrict__ EL)
{
    static_assert(NBM % PM == 0 && NBN % PN == 0, "patch divides grid");
    constexpr int XM = NBM / PM, XN = NBN / PN;
    static_assert(XM * XN * KS == 8, "patches x KS must equal 8 XCDs");
    static_assert(PM * PN == (NBM * NBN * KS) / 8, "slot count");

    __shared__ __align__(16) char smem[16640];
    unsigned short (*AsH)[40] = (unsigned short (*)[40])(smem);
    unsigned short (*BsH)[40] = (unsigned short (*)[40])(smem + 5120);
    unsigned short (*BsL)[40] = (unsigned short (*)[40])(smem + 10240);

    const int bid  = blockIdx.x;
    const int xcd  = bid & 7;
    const int slot = bid >> 3;
    const int ks   = xcd % KS;
    const int rest = xcd / KS;
    const int xn   = rest % XN;
    const int xm   = rest / XN;
    const int m_   = xm * PM + slot / PN;
    const int n_   = xn * PN + slot % PN;
    const int brow = m_ * 64;
    const int bcol = n_ * 64;
    const int koff = ks * Kper;

    const int tid  = threadIdx.x;
    const int wave = tid >> 6, lane = tid & 63;
    const int wr = wave >> 1, wc = wave & 1;
    const int lrow = lane & 15, kg = lane >> 4;

    const int srow = tid >> 2, sk8 = (tid & 3) << 3;

    uint4  pA0, pA1, pB0, pB1;
    float4 pF[2];

    auto LOAD = [&](int k0) {
        const size_t ga = (size_t)(brow + srow) * lda + k0 + sk8;
        if constexpr (AMODE == 1) {
            pA0 = *(const uint4*)(Ah + ga);
        } else if constexpr (AMODE == 4) {
            pA0 = *(const uint4*)(Ah + ga);
            pA1 = *(const uint4*)(Ah + ga + psz);
        } else {
            pF[0] = *(const float4*)(A + ga);
            pF[1] = *(const float4*)(A + ga + 4);
        }
        const size_t gb = (size_t)(bcol + srow) * ldb + k0 + sk8;
        pB0 = *(const uint4*)(Bh + gb);
        if constexpr (!BS) pB1 = *(const uint4*)(Bl + gb);
    };
    auto STORE = [&]() {
        if constexpr (AMODE == 1) {
            *(uint4*)&AsH[srow][sk8] = pA0;
        } else if constexpr (AMODE == 4) {
            half8 h0 = *(half8*)&pA0;
            half8 h1 = *(half8*)&pA1;
            half8 hs = h0 + h1;
            *(half8*)&AsH[srow][sk8] = hs;
        } else {
            float va[8];
            va[0] = pF[0].x; va[1] = pF[0].y; va[2] = pF[0].z; va[3] = pF[0].w;
            va[4] = pF[1].x; va[5] = pF[1].y; va[6] = pF[1].z; va[7] = pF[1].w;
            half8 h0;
            #pragma unroll
            for (int j = 0; j < 8; ++j) h0[j] = (_Float16)va[j];
            *(half8*)&AsH[srow][sk8] = h0;
        }
        *(uint4*)&BsH[srow][sk8] = pB0;
        if constexpr (!BS) *(uint4*)&BsL[srow][sk8] = pB1;
    };

    f32x4 acc[2][2];
    #pragma unroll
    for (int m = 0; m < 2; ++m)
        #pragma unroll
        for (int n = 0; n < 2; ++n)
            #pragma unroll
            for (int q = 0; q < 4; ++q) acc[m][n][q] = 0.0f;

    const int NK = Kper / 32;
    LOAD(koff);
    STORE();
    __syncthreads();

    for (int ki = 0; ki < NK; ++ki) {
        if (ki + 1 < NK) LOAD(koff + (ki + 1) * 32);

        half8 a[2], bh[2], bl[2];
        #pragma unroll
        for (int m = 0; m < 2; ++m)
            a[m] = *(const half8*)&AsH[wr * 32 + m * 16 + lrow][kg * 8];
        #pragma unroll
        for (int n = 0; n < 2; ++n) {
            const int c = wc * 32 + n * 16 + lrow;
            bh[n] = *(const half8*)&BsH[c][kg * 8];
            if constexpr (!BS) bl[n] = *(const half8*)&BsL[c][kg * 8];
        }
        #pragma unroll
        for (int m = 0; m < 2; ++m)
            #pragma unroll
            for (int n = 0; n < 2; ++n) {
                acc[m][n] = __builtin_amdgcn_mfma_f32_16x16x32_f16(a[m], bh[n], acc[m][n], 0, 0, 0);
                if constexpr (!BS)
                    acc[m][n] = __builtin_amdgcn_mfma_f32_16x16x32_f16(a[m], bl[n], acc[m][n], 0, 0, 0);
            }
        __syncthreads();
        if (ki + 1 < NK) { STORE(); __syncthreads(); }
    }

    // ---- transposed epilogue: acc -> LDS [64][65] -> whole-row float4 I/O ----
    float* eb = (float*)smem;
    #pragma unroll
    for (int m = 0; m < 2; ++m)
        #pragma unroll
        for (int n = 0; n < 2; ++n)
            #pragma unroll
            for (int r = 0; r < 4; ++r)
                eb[(wr * 32 + m * 16 + kg * 4 + r) * 65 + wc * 32 + n * 16 + lrow] = acc[m][n][r];
    __syncthreads();

    #pragma unroll
    for (int j = 0; j < 4; ++j) {
        const int row = wave * 16 + j * 4 + (lane >> 4);
        const int col = (lane & 15) * 4;
        const float4 v = *(const float4*)&eb[row * 65 + col];
        const size_t gi = (size_t)(brow + row) * ldc + bcol + col;
        if constexpr (EPI == 0) {
            *(float4*)(C + cks * ks + gi) = v;
            if constexpr (EMIT == 1) {
                us4 h;
                h.x = h_bits(v.x); h.y = h_bits(v.y);
                h.z = h_bits(v.z); h.w = h_bits(v.w);
                *(us4*)(Y2 + gi) = h;
            }
            if constexpr (EMIT == 2) {
                const HL a = split2h(v.x), b = split2h(v.y);
                const HL c2 = split2h(v.z), d = split2h(v.w);
                us4 h, l;
                h.x = a.h; l.x = a.l; h.y = b.h; l.y = b.l;
                h.z = c2.h; l.z = c2.l; h.w = d.h; l.w = d.l;
                *(us4*)(EH + gi) = h;
                *(us4*)(EL + gi) = l;
            }
        } else if constexpr (EPI == 4) {   // fp16 partial write (T-GEMM)
            us4 h;
            h.x = h_bits(v.x); h.y = h_bits(v.y);
            h.z = h_bits(v.z); h.w = h_bits(v.w);
            *(us4*)(Y2 + cks * ks + gi) = h;
        } else { // EPI == 3: ADMM w-update, fully coalesced streams
            const float4 f1 = *(const float4*)(F1 + gi);
            const float4 ww = *(const float4*)(Wio + gi);
            float wn0 = f1.x + ww.x - clampl(ww.x) - v.x;
            float wn1 = f1.y + ww.y - clampl(ww.y) - v.y;
            float wn2 = f1.z + ww.z - clampl(ww.z) - v.z;
            float wn3 = f1.w + ww.w - clampl(ww.w) - v.w;
            if constexpr (LASTZ) {
                float4 o;
                o.x = wn0 - clampl(wn0); o.y = wn1 - clampl(wn1);
                o.z = wn2 - clampl(wn2); o.w = wn3 - clampl(wn3);
                *(float4*)(OutZ + gi) = o;
            } else {
                float4 o; o.x = wn0; o.y = wn1; o.z = wn2; o.w = wn3;
                *(float4*)(Wio + gi) = o;
                us4 h;
                h.x = h_bits(f1.x + wn0 - 2.0f * clampl(wn0));
                h.y = h_bits(f1.y + wn1 - 2.0f * clampl(wn1));
                h.z = h_bits(f1.z + wn2 - 2.0f * clampl(wn2));
                h.w = h_bits(f1.w + wn3 - 2.0f * clampl(wn3));
                *(us4*)(Y2 + gi) = h;
            }
        }
    }
}

// Normalize rows of weight (3072x768); emit fp16 h/l of wn and wn^T.
__global__ __launch_bounds__(256)
void rownorm_kernel(const float* __restrict__ W,
                    unsigned short* __restrict__ wnH, unsigned short* __restrict__ wnL,
                    unsigned short* __restrict__ wnTH, unsigned short* __restrict__ wnTL)
{
    __shared__ float red[256];
    const int row = blockIdx.x;
    const int t = threadIdx.x;
    const float* wr = W + (size_t)row * NN_;
    float s = 0.0f;
    for (int k = t; k < NN_; k += 256) { const float w = wr[k]; s += w * w; }
    red[t] = s; __syncthreads();
    for (int off = 128; off > 0; off >>= 1) {
        if (t < off) red[t] += red[t + off];
        __syncthreads();
    }
    const float rn = 1.0f / sqrtf(red[0]);
    for (int k = t; k < NN_; k += 256) {
        const float v = wr[k] * rn;
        const HL s2 = split2h(v);
        wnH[(size_t)row * NN_ + k] = s2.h;
        wnL[(size_t)row * NN_ + k] = s2.l;
        wnTH[(size_t)k * MM + row] = s2.h;
        wnTL[(size_t)k * MM + row] = s2.l;
    }
}

__global__ __launch_bounds__(256)
void rowabs_kernel(const float* __restrict__ G, float* __restrict__ rowsum)
{
    __shared__ float red[256];
    const int row = blockIdx.x;
    const int t = threadIdx.x;
    const float* gr = G + (size_t)row * NN_;
    float s = 0.0f;
    for (int k = t; k < NN_; k += 256) s += fabsf(gr[k]);
    red[t] = s; __syncthreads();
    for (int off = 128; off > 0; off >>= 1) {
        if (t < off) red[t] += red[t + off];
        __syncthreads();
    }
    if (t == 0) rowsum[row] = red[0];
}

__global__ __launch_bounds__(256)
void cmax_kernel(const float* __restrict__ rowsum, float* __restrict__ cbuf)
{
    __shared__ float red[256];
    const int t = threadIdx.x;
    float mx = 0.0f;
    for (int k = t; k < NN_; k += 256) mx = fmaxf(mx, rowsum[k]);
    red[t] = mx; __syncthreads();
    for (int off = 128; off > 0; off >>= 1) {
        if (t < off) red[t] = fmaxf(red[t], red[t + off]);
        __syncthreads();
    }
    if (t == 0) cbuf[0] = 2.0f / (1.0f + red[0]);
}

__global__ __launch_bounds__(256)
void initdiag_kernel(float* __restrict__ X, const float* __restrict__ c)
{
    const int idx = blockIdx.x * 256 + threadIdx.x;
    const int p = idx / NN_, q = idx - p * NN_;
    X[idx] = (p == q) ? c[0] : 0.0f;
}

// dec = p0 + p1 (float4)
__global__ __launch_bounds__(256)
void add2_kernel(const float* __restrict__ p0, size_t ps, float* __restrict__ o)
{
    const size_t i = ((size_t)blockIdx.x * 256 + threadIdx.x) * 4;
    const float4 a = *(const float4*)(p0 + i);
    const float4 b = *(const float4*)(p0 + ps + i);
    float4 v;
    v.x = a.x + b.x; v.y = a.y + b.y;
    v.z = a.z + b.z; v.w = a.w + b.w;
    *(float4*)(o + i) = v;
}

extern "C" void kernel_launch(void* const* d_in, const int* in_sizes, int n_in,
                              void* d_out, int out_size, void* d_ws, size_t ws_size,
                              hipStream_t stream)
{
    const float* x = (const float*)d_in[0];   // (2048, 768)
    const float* w = (const float*)d_in[1];   // (3072, 768)

    float* out = (float*)d_out;
    float* z   = out;                          // (2048, 3072)
    float* dec = out + (size_t)BB * MM;        // (2048, 768)

    char* wsb = (char*)d_ws;
    size_t off = 0;
    auto alloc = [&](size_t bytes) -> void* {
        void* p = wsb + off;
        off += (bytes + 255) & ~(size_t)255;
        return p;
    };
    // --- persistent ---
    unsigned short* wnH  = (unsigned short*)alloc((size_t)MM * NN_ * 2);
    unsigned short* wnL  = (unsigned short*)alloc((size_t)MM * NN_ * 2);
    unsigned short* wnTH = (unsigned short*)alloc((size_t)MM * NN_ * 2);
    unsigned short* wnTL = (unsigned short*)alloc((size_t)MM * NN_ * 2);
    float* adotb = (float*)alloc((size_t)BB * MM * 4);
    float* wbuf  = (float*)alloc((size_t)BB * MM * 4);
    unsigned short* y2h = (unsigned short*)alloc((size_t)BB * MM * 2);
    unsigned short* QH  = (unsigned short*)alloc((size_t)NN_ * NN_ * 2);
    unsigned short* QL  = (unsigned short*)alloc((size_t)NN_ * NN_ * 2);
    unsigned short* RTH = (unsigned short*)alloc((size_t)MM * NN_ * 2);
    unsigned short* RTL = (unsigned short*)alloc((size_t)MM * NN_ * 2);
    unsigned short* Thp = (unsigned short*)alloc((size_t)2 * BB * NN_ * 2); // fp16 T partials
    // --- overlay: NS temps (dead after RT) aliased with Tp (decode partials) ---
    const size_t overlay = off;
    float* G  = (float*)alloc((size_t)NN_ * NN_ * 4);
    unsigned short* GH  = (unsigned short*)alloc((size_t)NN_ * NN_ * 2);
    unsigned short* GL  = (unsigned short*)alloc((size_t)NN_ * NN_ * 2);
    float* X0 = (float*)alloc((size_t)NN_ * NN_ * 4);
    float* X1 = (float*)alloc((size_t)NN_ * NN_ * 4);
    float* Yb = (float*)alloc((size_t)NN_ * NN_ * 4);
    unsigned short* YbH = (unsigned short*)alloc((size_t)NN_ * NN_ * 2);
    unsigned short* YbL = (unsigned short*)alloc((size_t)NN_ * NN_ * 2);
    float* rowsum = (float*)alloc(NN_ * 4);
    float* cbuf   = (float*)alloc(256);
    float* Pp = (float*)alloc((size_t)4 * NN_ * NN_ * 4);  // split-K f32 partials
    // Tp (2 x 2048x768 f32 = 12.6 MB) aliases the NS-temp region (~14.2 MB);
    // NS temps dead before first Tp use (RT GEMM f32 scratch / decode partials).
    float* Tp = (float*)(wsb + overlay);
    const size_t TPS = (size_t)BB * NN_;

    (void)hipMemsetAsync(wbuf, 0, (size_t)BB * MM * sizeof(float), stream);

    const dim3 blk(256);
    const dim3 gsk(NN_ / 64, NN_ / 64, 4);
    const int  RED = (NN_ * NN_ / 4) / 256;   // 576

    rownorm_kernel<<<MM, blk, 0, stream>>>(w, wnH, wnL, wnTH, wnTL);

    // adotb = x @ wn^T (M2048 N3072 K768); emit y2_0 = fp16(adotb). B 2-term.
    gemm_big<32,48,1,8,24,0,0,0,1,0><<<1536, blk, 0, stream>>>(
        x, nullptr, NN_, 0, wnH, wnL, NN_, adotb, MM, 0, NN_,
        nullptr, nullptr, nullptr, y2h, nullptr, nullptr);

    // G = wn^T wn + I (768x768, K=3072), split-K=4 + reduce(+I, split)
    gemm_sk<1><<<gsk, blk, 0, stream>>>(
        nullptr, wnTH, wnTL, MM, wnTH, wnTL, MM, Pp, MM / 4);
    red_ns<1><<<RED, blk, 0, stream>>>(Pp, nullptr, G, GH, GL);

    rowabs_kernel<<<NN_, blk, 0, stream>>>(G, rowsum);
    cmax_kernel<<<1, blk, 0, stream>>>(rowsum, cbuf);
    initdiag_kernel<<<(NN_ * NN_) / 256, blk, 0, stream>>>(X0, cbuf);

    // Newton-Schulz X <- 2X - XGX, 7 iterations, split-K=4 per GEMM
    float* Xc = X0;
    float* Xn = X1;
    for (int it = 0; it < 7; ++it) {
        gemm_sk<0><<<gsk, blk, 0, stream>>>(
            Xc, nullptr, nullptr, NN_, GH, GL, NN_, Pp, NN_ / 4);
        red_ns<0><<<RED, blk, 0, stream>>>(Pp, nullptr, Yb, YbH, YbL);
        gemm_sk<0><<<gsk, blk, 0, stream>>>(
            Xc, nullptr, nullptr, NN_, YbH, YbL, NN_, Pp, NN_ / 4);
        red_ns<2><<<RED, blk, 0, stream>>>(Pp, Xc, Xn, QH, QL);
        float* t = Xc; Xc = Xn; Xn = t;
    }
    // QH/QL = fp16 split of G^{-1}

    // RT = wn @ Ginv (M3072 N768 K768); emit RTH/RTL (f32 scratch to Tp). B 2-term.
    gemm_big<48,12,1,12,6,1,0,0,2,0><<<576, blk, 0, stream>>>(
        nullptr, wnH, NN_, 0, QH, QL, NN_, Tp, NN_, 0, NN_,
        nullptr, nullptr, nullptr, nullptr, RTH, RTL);

    // ADMM loop: T = y2 @ wn -> fp16 partials Thp (KS=2, B SINGLE fp16);
    // w-update sums the fp16 pair in-register (AMODE=4, B=RT SINGLE fp16)
    for (int it = 0; it < 20; ++it) {
        gemm_big<32,12,2,16,6,1,1,4,0,0><<<768, blk, 0, stream>>>(
            nullptr, y2h, MM, 0, wnTH, nullptr, MM, nullptr, NN_, TPS, MM / 2,
            nullptr, nullptr, nullptr, Thp, nullptr, nullptr);
        if (it < 19) {
            gemm_big<32,48,1,8,24,4,1,3,0,0><<<1536, blk, 0, stream>>>(
                nullptr, Thp, NN_, TPS, RTH, nullptr, NN_, nullptr, MM, 0, NN_,
                adotb, wbuf, nullptr, y2h, nullptr, nullptr);
        } else {
            gemm_big<32,48,1,8,24,4,1,3,0,1><<<1536, blk, 0, stream>>>(
                nullptr, Thp, NN_, TPS, RTH, nullptr, NN_, nullptr, MM, 0, NN_,
                adotb, wbuf, z, y2h, nullptr, nullptr);
        }
    }

    // decoded = z @ wn (M2048 N768 K3072), KS=2 f32 partials + reduce. B 2-term.
    gemm_big<32,12,2,16,6,0,0,0,0,0><<<768, blk, 0, stream>>>(
        z, nullptr, MM, 0, wnTH, wnTL, MM, Tp, NN_, TPS, MM / 2,
        nullptr, nullptr, nullptr, nullptr, nullptr, nullptr);
    add2_kernel<<<(BB * NN_ / 4) / 256, blk, 0, stream>>>(Tp, TPS, dec);
}

// Round 17
// 1684.399 us; speedup vs baseline: 3.1739x; 1.0363x over previous
//
#include <hip/hip_runtime.h>
#include <math.h>

#define BB   2048
#define NN_  768
#define MM   3072
#define LAMBD 0.1f

typedef __attribute__((ext_vector_type(8))) _Float16 half8;
typedef __attribute__((ext_vector_type(4))) float  f32x4;
typedef __attribute__((ext_vector_type(4))) unsigned short us4;

union HB { _Float16 f; unsigned short u; };
struct HL { unsigned short h, l; };

__device__ __forceinline__ unsigned short h_bits(float f) {
    HB b; b.f = (_Float16)f; return b.u;
}
__device__ __forceinline__ HL split2h(float f) {
    HL r;
    HB b; b.f = (_Float16)f;
    r.h = b.u;
    const float fh = (float)b.f;
    HB c; c.f = (_Float16)(f - fh);
    r.l = c.u;
    return r;
}
__device__ __forceinline__ float clampl(float x) {
    return fminf(fmaxf(x, -LAMBD), LAMBD);
}
__device__ __forceinline__ float4 cvt4h(const unsigned short* p) {
    const us4 u = *(const us4*)p;
    HB a, b, c, d;
    a.u = u.x; b.u = u.y; c.u = u.z; d.u = u.w;
    float4 f;
    f.x = (float)a.f; f.y = (float)b.f; f.z = (float)c.f; f.w = (float)d.f;
    return f;
}

// ---------------------------------------------------------------------------
// Split-K small GEMM (768x768 out, fp16 3-term), 64x64 tile, reg-prefetch,
// single LDS buffer + transposed (coalesced) epilogue. Grid: (12, 12, KS).
// (R12-proven form, unchanged.)
// ---------------------------------------------------------------------------
template<int APRE>
__global__ __launch_bounds__(256)
void gemm_sk(const float* __restrict__ A,
             const unsigned short* __restrict__ Ah,
             const unsigned short* __restrict__ Al,
             int lda,
             const unsigned short* __restrict__ Bh,
             const unsigned short* __restrict__ Bl,
             int ldb,
             float* __restrict__ P, int Kper)
{
    __shared__ __align__(16) char smem[20480];
    unsigned short (*AsH)[40] = (unsigned short (*)[40])(smem);
    unsigned short (*AsL)[40] = (unsigned short (*)[40])(smem + 5120);
    unsigned short (*BsH)[40] = (unsigned short (*)[40])(smem + 10240);
    unsigned short (*BsL)[40] = (unsigned short (*)[40])(smem + 15360);

    const int tid  = threadIdx.x;
    const int brow = blockIdx.y * 64;
    const int bcol = blockIdx.x * 64;
    const int koff = blockIdx.z * Kper;
    const int wave = tid >> 6, lane = tid & 63;
    const int wr = wave >> 1, wc = wave & 1;
    const int lrow = lane & 15, kg = lane >> 4;

    const int sk4  = (tid & 7) << 2;

    us4   rAh[2], rAl[2], rBh[2], rBl[2];
    float4 rAf[2];

    auto LOAD = [&](int k0) {
        #pragma unroll
        for (int p = 0; p < 2; ++p) {
            const int row = (p * 256 + tid) >> 3;
            const size_t ga = (size_t)(brow + row) * lda + k0 + sk4;
            const size_t gb = (size_t)(bcol + row) * ldb + k0 + sk4;
            if constexpr (APRE) {
                rAh[p] = *(const us4*)(Ah + ga);
                rAl[p] = *(const us4*)(Al + ga);
            } else {
                rAf[p] = *(const float4*)(A + ga);
            }
            rBh[p] = *(const us4*)(Bh + gb);
            rBl[p] = *(const us4*)(Bl + gb);
        }
    };
    auto STORE = [&]() {
        #pragma unroll
        for (int p = 0; p < 2; ++p) {
            const int row = (p * 256 + tid) >> 3;
            if constexpr (APRE) {
                *(us4*)&AsH[row][sk4] = rAh[p];
                *(us4*)&AsL[row][sk4] = rAl[p];
            } else {
                const HL sx = split2h(rAf[p].x), sy = split2h(rAf[p].y);
                const HL sz = split2h(rAf[p].z), sw = split2h(rAf[p].w);
                us4 h, l;
                h.x = sx.h; l.x = sx.l; h.y = sy.h; l.y = sy.l;
                h.z = sz.h; l.z = sz.l; h.w = sw.h; l.w = sw.l;
                *(us4*)&AsH[row][sk4] = h;
                *(us4*)&AsL[row][sk4] = l;
            }
            *(us4*)&BsH[row][sk4] = rBh[p];
            *(us4*)&BsL[row][sk4] = rBl[p];
        }
    };

    f32x4 acc[2][2];
    #pragma unroll
    for (int m = 0; m < 2; ++m)
        #pragma unroll
        for (int n = 0; n < 2; ++n)
            #pragma unroll
            for (int q = 0; q < 4; ++q) acc[m][n][q] = 0.0f;

    const int NK = Kper / 32;
    LOAD(koff);
    STORE();
    __syncthreads();

    for (int ki = 0; ki < NK; ++ki) {
        if (ki + 1 < NK) LOAD(koff + (ki + 1) * 32);

        half8 ahi[2], alo[2], bhi[2], blo[2];
        #pragma unroll
        for (int m = 0; m < 2; ++m) {
            const int r = wr * 32 + m * 16 + lrow;
            ahi[m] = *(const half8*)&AsH[r][kg * 8];
            alo[m] = *(const half8*)&AsL[r][kg * 8];
        }
        #pragma unroll
        for (int n = 0; n < 2; ++n) {
            const int c = wc * 32 + n * 16 + lrow;
            bhi[n] = *(const half8*)&BsH[c][kg * 8];
            blo[n] = *(const half8*)&BsL[c][kg * 8];
        }
        #pragma unroll
        for (int m = 0; m < 2; ++m)
            #pragma unroll
            for (int n = 0; n < 2; ++n) {
                acc[m][n] = __builtin_amdgcn_mfma_f32_16x16x32_f16(ahi[m], bhi[n], acc[m][n], 0, 0, 0);
                acc[m][n] = __builtin_amdgcn_mfma_f32_16x16x32_f16(ahi[m], blo[n], acc[m][n], 0, 0, 0);
                acc[m][n] = __builtin_amdgcn_mfma_f32_16x16x32_f16(alo[m], bhi[n], acc[m][n], 0, 0, 0);
            }
        __syncthreads();
        if (ki + 1 < NK) { STORE(); __syncthreads(); }
    }

    // transposed epilogue: acc -> LDS [64][65] -> coalesced float4 rows
    float* eb = (float*)smem;
    #pragma unroll
    for (int m = 0; m < 2; ++m)
        #pragma unroll
        for (int n = 0; n < 2; ++n)
            #pragma unroll
            for (int r = 0; r < 4; ++r)
                eb[(wr * 32 + m * 16 + kg * 4 + r) * 65 + wc * 32 + n * 16 + lrow] = acc[m][n][r];
    __syncthreads();
    float* Pk = P + (size_t)blockIdx.z * NN_ * NN_;
    #pragma unroll
    for (int j = 0; j < 4; ++j) {
        const int row = wave * 16 + j * 4 + (lane >> 4);
        const int col = (lane & 15) * 4;
        const float4 v = *(const float4*)&eb[row * 65 + col];
        *(float4*)(Pk + (size_t)(brow + row) * NN_ + bcol + col) = v;
    }
}

// Reduce 4 split-K partials with epilogue. MODE: 0 plain, 1 +I, 2 2*E1-sum.
template<int MODE>
__global__ __launch_bounds__(256)
void red_ns(const float* __restrict__ P,
            const float* __restrict__ E1,
            float* __restrict__ C,
            unsigned short* __restrict__ Ch,
            unsigned short* __restrict__ Cl)
{
    const size_t i4 = ((size_t)blockIdx.x * 256 + threadIdx.x) * 4;
    const size_t sz = (size_t)NN_ * NN_;
    float4 s = *(const float4*)(P + i4);
    const float4 s1 = *(const float4*)(P + sz + i4);
    const float4 s2 = *(const float4*)(P + 2 * sz + i4);
    const float4 s3 = *(const float4*)(P + 3 * sz + i4);
    s.x = (s.x + s1.x) + (s2.x + s3.x);
    s.y = (s.y + s1.y) + (s2.y + s3.y);
    s.z = (s.z + s1.z) + (s2.z + s3.z);
    s.w = (s.w + s1.w) + (s2.w + s3.w);
    float v[4] = {s.x, s.y, s.z, s.w};
    if constexpr (MODE == 1) {
        const int row = (int)(i4 / NN_);
        const int col = (int)(i4 - (size_t)row * NN_);
        #pragma unroll
        for (int j = 0; j < 4; ++j) if (row == col + j) v[j] += 1.0f;
    }
    if constexpr (MODE == 2) {
        const float4 e = *(const float4*)(E1 + i4);
        v[0] = 2.0f * e.x - v[0]; v[1] = 2.0f * e.y - v[1];
        v[2] = 2.0f * e.z - v[2]; v[3] = 2.0f * e.w - v[3];
    }
    float4 o; o.x = v[0]; o.y = v[1]; o.z = v[2]; o.w = v[3];
    *(float4*)(C + i4) = o;
    us4 h, l;
    const HL a = split2h(v[0]), b = split2h(v[1]);
    const HL c = split2h(v[2]), d = split2h(v[3]);
    h.x = a.h; l.x = a.l; h.y = b.h; l.y = b.l;
    h.z = c.h; l.z = c.l; h.w = d.h; l.w = d.l;
    *(us4*)(Ch + i4) = h;
    *(us4*)(Cl + i4) = l;
}

// ---------------------------------------------------------------------------
// Big fp16 GEMM: 64x64 tile, 4 waves (32x32), BK=32, reg-prefetch,
// single LDS buffer + transposed (coalesced) epilogue. (R12 structure.)
// AMODE: 0 f32 A -> cvt; 1 pre-cvt fp16 (Ah); 4 fp16 pair Ah/Ah+psz summed.
// BS: 1 = B single fp16 (Bh only); 0 = B 2-term h/l.
// EPI: 0 C=acc f32 (+EMIT); 3 ADMM w-update on SINGLE-fp16 state streams;
//      4 fp16 partial -> Y2[cks*ks+gi].
// EMIT: 0 none, 1 Y2=fp16(acc), 2 EH/EL=split(acc), 4 Y2+EHonly=fp16(acc), NO C.
// Grid: flat NBM*NBN*KS; per-XCD 2D patch PM x PN for L2 reuse.
// ---------------------------------------------------------------------------
template<int NBM, int NBN, int KS, int PM, int PN, int AMODE, int BS, int EPI, int EMIT, int LASTZ>
__global__ __launch_bounds__(256)
void gemm_big(const float* __restrict__ A,
              const unsigned short* __restrict__ Ah,
              int lda, size_t psz,
              const unsigned short* __restrict__ Bh,
              const unsigned short* __restrict__ Bl,
              int ldb,
              float* __restrict__ C, int ldc, size_t cks, int Kper,
              const unsigned short* __restrict__ F1h,   // fp16 adotb (EPI=3)
              unsigned short* __restrict__ Wh,          // fp16 w state (EPI=3, in/out)
              float* __restrict__ OutZ,
              unsigned short* __restrict__ Y2,
              unsigned short* __restrict__ EH,
              unsigned short* __restrict__ EL)
{
    static_assert(NBM % PM == 0 && NBN % PN == 0, "patch divides grid");
    constexpr int XM = NBM / PM, XN = NBN / PN;
    static_assert(XM * XN * KS == 8, "patches x KS must equal 8 XCDs");
    static_assert(PM * PN == (NBM * NBN * KS) / 8, "slot count");

    __shared__ __align__(16) char smem[16640];
    unsigned short (*AsH)[40] = (unsigned short (*)[40])(smem);
    unsigned short (*BsH)[40] = (unsigned short (*)[40])(smem + 5120);
    unsigned short (*BsL)[40] = (unsigned short (*)[40])(smem + 10240);

    const int bid  = blockIdx.x;
    const int xcd  = bid & 7;
    const int slot = bid >> 3;
    const int ks   = xcd % KS;
    const int rest = xcd / KS;
    const int xn   = rest % XN;
    const int xm   = rest / XN;
    const int m_   = xm * PM + slot / PN;
    const int n_   = xn * PN + slot % PN;
    const int brow = m_ * 64;
    const int bcol = n_ * 64;
    const int koff = ks * Kper;

    const int tid  = threadIdx.x;
    const int wave = tid >> 6, lane = tid & 63;
    const int wr = wave >> 1, wc = wave & 1;
    const int lrow = lane & 15, kg = lane >> 4;

    const int srow = tid >> 2, sk8 = (tid & 3) << 3;

    uint4  pA0, pA1, pB0, pB1;
    float4 pF[2];

    auto LOAD = [&](int k0) {
        const size_t ga = (size_t)(brow + srow) * lda + k0 + sk8;
        if constexpr (AMODE == 1) {
            pA0 = *(const uint4*)(Ah + ga);
        } else if constexpr (AMODE == 4) {
            pA0 = *(const uint4*)(Ah + ga);
            pA1 = *(const uint4*)(Ah + ga + psz);
        } else {
            pF[0] = *(const float4*)(A + ga);
            pF[1] = *(const float4*)(A + ga + 4);
        }
        const size_t gb = (size_t)(bcol + srow) * ldb + k0 + sk8;
        pB0 = *(const uint4*)(Bh + gb);
        if constexpr (!BS) pB1 = *(const uint4*)(Bl + gb);
    };
    auto STORE = [&]() {
        if constexpr (AMODE == 1) {
            *(uint4*)&AsH[srow][sk8] = pA0;
        } else if constexpr (AMODE == 4) {
            half8 h0 = *(half8*)&pA0;
            half8 h1 = *(half8*)&pA1;
            half8 hs = h0 + h1;
            *(half8*)&AsH[srow][sk8] = hs;
        } else {
            float va[8];
            va[0] = pF[0].x; va[1] = pF[0].y; va[2] = pF[0].z; va[3] = pF[0].w;
            va[4] = pF[1].x; va[5] = pF[1].y; va[6] = pF[1].z; va[7] = pF[1].w;
            half8 h0;
            #pragma unroll
            for (int j = 0; j < 8; ++j) h0[j] = (_Float16)va[j];
            *(half8*)&AsH[srow][sk8] = h0;
        }
        *(uint4*)&BsH[srow][sk8] = pB0;
        if constexpr (!BS) *(uint4*)&BsL[srow][sk8] = pB1;
    };

    f32x4 acc[2][2];
    #pragma unroll
    for (int m = 0; m < 2; ++m)
        #pragma unroll
        for (int n = 0; n < 2; ++n)
            #pragma unroll
            for (int q = 0; q < 4; ++q) acc[m][n][q] = 0.0f;

    const int NK = Kper / 32;
    LOAD(koff);
    STORE();
    __syncthreads();

    for (int ki = 0; ki < NK; ++ki) {
        if (ki + 1 < NK) LOAD(koff + (ki + 1) * 32);

        half8 a[2], bh[2], bl[2];
        #pragma unroll
        for (int m = 0; m < 2; ++m)
            a[m] = *(const half8*)&AsH[wr * 32 + m * 16 + lrow][kg * 8];
        #pragma unroll
        for (int n = 0; n < 2; ++n) {
            const int c = wc * 32 + n * 16 + lrow;
            bh[n] = *(const half8*)&BsH[c][kg * 8];
            if constexpr (!BS) bl[n] = *(const half8*)&BsL[c][kg * 8];
        }
        #pragma unroll
        for (int m = 0; m < 2; ++m)
            #pragma unroll
            for (int n = 0; n < 2; ++n) {
                acc[m][n] = __builtin_amdgcn_mfma_f32_16x16x32_f16(a[m], bh[n], acc[m][n], 0, 0, 0);
                if constexpr (!BS)
                    acc[m][n] = __builtin_amdgcn_mfma_f32_16x16x32_f16(a[m], bl[n], acc[m][n], 0, 0, 0);
            }
        __syncthreads();
        if (ki + 1 < NK) { STORE(); __syncthreads(); }
    }

    // ---- transposed epilogue: acc -> LDS [64][65] -> whole-row float4 I/O ----
    float* eb = (float*)smem;
    #pragma unroll
    for (int m = 0; m < 2; ++m)
        #pragma unroll
        for (int n = 0; n < 2; ++n)
            #pragma unroll
            for (int r = 0; r < 4; ++r)
                eb[(wr * 32 + m * 16 + kg * 4 + r) * 65 + wc * 32 + n * 16 + lrow] = acc[m][n][r];
    __syncthreads();

    #pragma unroll
    for (int j = 0; j < 4; ++j) {
        const int row = wave * 16 + j * 4 + (lane >> 4);
        const int col = (lane & 15) * 4;
        const float4 v = *(const float4*)&eb[row * 65 + col];
        const size_t gi = (size_t)(brow + row) * ldc + bcol + col;
        if constexpr (EPI == 0) {
            if constexpr (EMIT != 4)
                *(float4*)(C + cks * ks + gi) = v;
            if constexpr (EMIT == 1) {
                us4 h;
                h.x = h_bits(v.x); h.y = h_bits(v.y);
                h.z = h_bits(v.z); h.w = h_bits(v.w);
                *(us4*)(Y2 + gi) = h;
            }
            if constexpr (EMIT == 2) {
                const HL a = split2h(v.x), b = split2h(v.y);
                const HL c2 = split2h(v.z), d = split2h(v.w);
                us4 h, l;
                h.x = a.h; l.x = a.l; h.y = b.h; l.y = b.l;
                h.z = c2.h; l.z = c2.l; h.w = d.h; l.w = d.l;
                *(us4*)(EH + gi) = h;
                *(us4*)(EL + gi) = l;
            }
            if constexpr (EMIT == 4) {    // fp16 value to BOTH y2 and adh
                us4 h;
                h.x = h_bits(v.x); h.y = h_bits(v.y);
                h.z = h_bits(v.z); h.w = h_bits(v.w);
                *(us4*)(Y2 + gi) = h;
                *(us4*)(EH + gi) = h;
            }
        } else if constexpr (EPI == 4) {   // fp16 partial write (T-GEMM)
            us4 h;
            h.x = h_bits(v.x); h.y = h_bits(v.y);
            h.z = h_bits(v.z); h.w = h_bits(v.w);
            *(us4*)(Y2 + cks * ks + gi) = h;
        } else { // EPI == 3: ADMM w-update, single-fp16 state streams
            const float4 f1 = cvt4h(F1h + gi);
            const float4 ww = cvt4h(Wh + gi);
            const float f1v[4] = {f1.x, f1.y, f1.z, f1.w};
            const float wwv[4] = {ww.x, ww.y, ww.z, ww.w};
            const float vv[4]  = {v.x, v.y, v.z, v.w};
            float wn[4];
            #pragma unroll
            for (int q = 0; q < 4; ++q)
                wn[q] = f1v[q] + wwv[q] - clampl(wwv[q]) - vv[q];
            if constexpr (LASTZ) {
                float4 o;
                o.x = wn[0] - clampl(wn[0]); o.y = wn[1] - clampl(wn[1]);
                o.z = wn[2] - clampl(wn[2]); o.w = wn[3] - clampl(wn[3]);
                *(float4*)(OutZ + gi) = o;
            } else {
                us4 hh, y;
                #pragma unroll
                for (int q = 0; q < 4; ++q) {
                    ((unsigned short*)&hh)[q] = h_bits(wn[q]);
                    ((unsigned short*)&y)[q]  = h_bits(f1v[q] + wn[q] - 2.0f * clampl(wn[q]));
                }
                *(us4*)(Wh + gi) = hh;
                *(us4*)(Y2 + gi) = y;
            }
        }
    }
}

// Normalize rows of weight (3072x768); emit fp16 h/l of wn and wn^T.
__global__ __launch_bounds__(256)
void rownorm_kernel(const float* __restrict__ W,
                    unsigned short* __restrict__ wnH, unsigned short* __restrict__ wnL,
                    unsigned short* __restrict__ wnTH, unsigned short* __restrict__ wnTL)
{
    __shared__ float red[256];
    const int row = blockIdx.x;
    const int t = threadIdx.x;
    const float* wr = W + (size_t)row * NN_;
    float s = 0.0f;
    for (int k = t; k < NN_; k += 256) { const float w = wr[k]; s += w * w; }
    red[t] = s; __syncthreads();
    for (int off = 128; off > 0; off >>= 1) {
        if (t < off) red[t] += red[t + off];
        __syncthreads();
    }
    const float rn = 1.0f / sqrtf(red[0]);
    for (int k = t; k < NN_; k += 256) {
        const float v = wr[k] * rn;
        const HL s2 = split2h(v);
        wnH[(size_t)row * NN_ + k] = s2.h;
        wnL[(size_t)row * NN_ + k] = s2.l;
        wnTH[(size_t)k * MM + row] = s2.h;
        wnTL[(size_t)k * MM + row] = s2.l;
    }
}

__global__ __launch_bounds__(256)
void rowabs_kernel(const float* __restrict__ G, float* __restrict__ rowsum)
{
    __shared__ float red[256];
    const int row = blockIdx.x;
    const int t = threadIdx.x;
    const float* gr = G + (size_t)row * NN_;
    float s = 0.0f;
    for (int k = t; k < NN_; k += 256) s += fabsf(gr[k]);
    red[t] = s; __syncthreads();
    for (int off = 128; off > 0; off >>= 1) {
        if (t < off) red[t] += red[t + off];
        __syncthreads();
    }
    if (t == 0) rowsum[row] = red[0];
}

__global__ __launch_bounds__(256)
void cmax_kernel(const float* __restrict__ rowsum, float* __restrict__ cbuf)
{
    __shared__ float red[256];
    const int t = threadIdx.x;
    float mx = 0.0f;
    for (int k = t; k < NN_; k += 256) mx = fmaxf(mx, rowsum[k]);
    red[t] = mx; __syncthreads();
    for (int off = 128; off > 0; off >>= 1) {
        if (t < off) red[t] = fmaxf(red[t], red[t + off]);
        __syncthreads();
    }
    if (t == 0) cbuf[0] = 2.0f / (1.0f + red[0]);
}

__global__ __launch_bounds__(256)
void initdiag_kernel(float* __restrict__ X, const float* __restrict__ c)
{
    const int idx = blockIdx.x * 256 + threadIdx.x;
    const int p = idx / NN_, q = idx - p * NN_;
    X[idx] = (p == q) ? c[0] : 0.0f;
}

// dec = p0 + p1 (float4)
__global__ __launch_bounds__(256)
void add2_kernel(const float* __restrict__ p0, size_t ps, float* __restrict__ o)
{
    const size_t i = ((size_t)blockIdx.x * 256 + threadIdx.x) * 4;
    const float4 a = *(const float4*)(p0 + i);
    const float4 b = *(const float4*)(p0 + ps + i);
    float4 v;
    v.x = a.x + b.x; v.y = a.y + b.y;
    v.z = a.z + b.z; v.w = a.w + b.w;
    *(float4*)(o + i) = v;
}

extern "C" void kernel_launch(void* const* d_in, const int* in_sizes, int n_in,
                              void* d_out, int out_size, void* d_ws, size_t ws_size,
                              hipStream_t stream)
{
    const float* x = (const float*)d_in[0];   // (2048, 768)
    const float* w = (const float*)d_in[1];   // (3072, 768)

    float* out = (float*)d_out;
    float* z   = out;                          // (2048, 3072)
    float* dec = out + (size_t)BB * MM;        // (2048, 768)

    char* wsb = (char*)d_ws;
    size_t off = 0;
    auto alloc = [&](size_t bytes) -> void* {
        void* p = wsb + off;
        off += (bytes + 255) & ~(size_t)255;
        return p;
    };
    // --- persistent ---
    unsigned short* wnH  = (unsigned short*)alloc((size_t)MM * NN_ * 2);
    unsigned short* wnL  = (unsigned short*)alloc((size_t)MM * NN_ * 2);
    unsigned short* wnTH = (unsigned short*)alloc((size_t)MM * NN_ * 2);
    unsigned short* wnTL = (unsigned short*)alloc((size_t)MM * NN_ * 2);
    unsigned short* adh  = (unsigned short*)alloc((size_t)BB * MM * 2);  // fp16 adotb
    unsigned short* wbh  = (unsigned short*)alloc((size_t)BB * MM * 2);  // fp16 w state
    unsigned short* y2h  = (unsigned short*)alloc((size_t)BB * MM * 2);
    unsigned short* QH  = (unsigned short*)alloc((size_t)NN_ * NN_ * 2);
    unsigned short* QL  = (unsigned short*)alloc((size_t)NN_ * NN_ * 2);
    unsigned short* RTH = (unsigned short*)alloc((size_t)MM * NN_ * 2);
    unsigned short* RTL = (unsigned short*)alloc((size_t)MM * NN_ * 2);
    unsigned short* Thp = (unsigned short*)alloc((size_t)2 * BB * NN_ * 2); // fp16 T partials
    // --- overlay: NS temps (dead after RT) aliased with Tp (decode partials) ---
    const size_t overlay = off;
    float* G  = (float*)alloc((size_t)NN_ * NN_ * 4);
    unsigned short* GH  = (unsigned short*)alloc((size_t)NN_ * NN_ * 2);
    unsigned short* GL  = (unsigned short*)alloc((size_t)NN_ * NN_ * 2);
    float* X0 = (float*)alloc((size_t)NN_ * NN_ * 4);
    float* X1 = (float*)alloc((size_t)NN_ * NN_ * 4);
    float* Yb = (float*)alloc((size_t)NN_ * NN_ * 4);
    unsigned short* YbH = (unsigned short*)alloc((size_t)NN_ * NN_ * 2);
    unsigned short* YbL = (unsigned short*)alloc((size_t)NN_ * NN_ * 2);
    float* rowsum = (float*)alloc(NN_ * 4);
    float* cbuf   = (float*)alloc(256);
    float* Pp = (float*)alloc((size_t)4 * NN_ * NN_ * 4);  // split-K f32 partials
    // Tp (2 x 2048x768 f32 = 12.6 MB) aliases the NS-temp region (~14.2 MB);
    // NS temps dead before first Tp use (RT GEMM f32 scratch / decode partials).
    float* Tp = (float*)(wsb + overlay);
    const size_t TPS = (size_t)BB * NN_;

    (void)hipMemsetAsync(wbh, 0, (size_t)BB * MM * sizeof(unsigned short), stream);

    const dim3 blk(256);
    const dim3 gsk(NN_ / 64, NN_ / 64, 4);
    const int  RED = (NN_ * NN_ / 4) / 256;   // 576

    rownorm_kernel<<<MM, blk, 0, stream>>>(w, wnH, wnL, wnTH, wnTL);

    // adotb = x @ wn^T (M2048 N3072 K768); emit y2_0 AND adh (fp16, no f32 C).
    // B 2-term for accuracy (single rounding of adotb into fp16).
    gemm_big<32,48,1,8,24,0,0,0,4,0><<<1536, blk, 0, stream>>>(
        x, nullptr, NN_, 0, wnH, wnL, NN_, nullptr, MM, 0, NN_,
        nullptr, nullptr, nullptr, y2h, adh, nullptr);

    // G = wn^T wn + I (768x768, K=3072), split-K=4 + reduce(+I, split)
    gemm_sk<1><<<gsk, blk, 0, stream>>>(
        nullptr, wnTH, wnTL, MM, wnTH, wnTL, MM, Pp, MM / 4);
    red_ns<1><<<RED, blk, 0, stream>>>(Pp, nullptr, G, GH, GL);

    rowabs_kernel<<<NN_, blk, 0, stream>>>(G, rowsum);
    cmax_kernel<<<1, blk, 0, stream>>>(rowsum, cbuf);
    initdiag_kernel<<<(NN_ * NN_) / 256, blk, 0, stream>>>(X0, cbuf);

    // Newton-Schulz X <- 2X - XGX, 7 iterations, split-K=4 per GEMM
    float* Xc = X0;
    float* Xn = X1;
    for (int it = 0; it < 7; ++it) {
        gemm_sk<0><<<gsk, blk, 0, stream>>>(
            Xc, nullptr, nullptr, NN_, GH, GL, NN_, Pp, NN_ / 4);
        red_ns<0><<<RED, blk, 0, stream>>>(Pp, nullptr, Yb, YbH, YbL);
        gemm_sk<0><<<gsk, blk, 0, stream>>>(
            Xc, nullptr, nullptr, NN_, YbH, YbL, NN_, Pp, NN_ / 4);
        red_ns<2><<<RED, blk, 0, stream>>>(Pp, Xc, Xn, QH, QL);
        float* t = Xc; Xc = Xn; Xn = t;
    }
    // QH/QL = fp16 split of G^{-1}

    // RT = wn @ Ginv (M3072 N768 K768); emit RTH/RTL (f32 scratch to Tp). B 2-term.
    gemm_big<48,12,1,12,6,1,0,0,2,0><<<576, blk, 0, stream>>>(
        nullptr, wnH, NN_, 0, QH, QL, NN_, Tp, NN_, 0, NN_,
        nullptr, nullptr, nullptr, nullptr, RTH, RTL);

    // ADMM loop: T = y2 @ wn -> fp16 partials Thp (KS=2, B single fp16);
    // w-update: A = Thp pair summed (AMODE=4), B = RT single fp16,
    //           state streams adh/wbh single fp16.
    for (int it = 0; it < 20; ++it) {
        gemm_big<32,12,2,16,6,1,1,4,0,0><<<768, blk, 0, stream>>>(
            nullptr, y2h, MM, 0, wnTH, nullptr, MM, nullptr, NN_, TPS, MM / 2,
            nullptr, nullptr, nullptr, Thp, nullptr, nullptr);
        if (it < 19) {
            gemm_big<32,48,1,8,24,4,1,3,0,0><<<1536, blk, 0, stream>>>(
                nullptr, Thp, NN_, TPS, RTH, nullptr, NN_, nullptr, MM, 0, NN_,
                adh, wbh, nullptr, y2h, nullptr, nullptr);
        } else {
            gemm_big<32,48,1,8,24,4,1,3,0,1><<<1536, blk, 0, stream>>>(
                nullptr, Thp, NN_, TPS, RTH, nullptr, NN_, nullptr, MM, 0, NN_,
                adh, wbh, z, y2h, nullptr, nullptr);
        }
    }

    // decoded = z @ wn (M2048 N768 K3072), KS=2 f32 partials + reduce. B 2-term.
    gemm_big<32,12,2,16,6,0,0,0,0,0><<<768, blk, 0, stream>>>(
        z, nullptr, MM, 0, wnTH, wnTL, MM, Tp, NN_, TPS, MM / 2,
        nullptr, nullptr, nullptr, nullptr, nullptr, nullptr);
    add2_kernel<<<(BB * NN_ / 4) / 256, blk, 0, stream>>>(Tp, TPS, dec);
}

// Round 18
// 1399.103 us; speedup vs baseline: 3.8211x; 1.2039x over previous
//
#include <hip/hip_runtime.h>
#include <math.h>

#define BB   2048
#define NN_  768
#define MM   3072
#define LAMBD 0.1f

typedef __attribute__((ext_vector_type(8))) _Float16 half8;
typedef __attribute__((ext_vector_type(4))) float  f32x4;
typedef __attribute__((ext_vector_type(4))) unsigned short us4;

union HB { _Float16 f; unsigned short u; };
struct HL { unsigned short h, l; };

__device__ __forceinline__ unsigned short h_bits(float f) {
    HB b; b.f = (_Float16)f; return b.u;
}
__device__ __forceinline__ HL split2h(float f) {
    HL r;
    HB b; b.f = (_Float16)f;
    r.h = b.u;
    const float fh = (float)b.f;
    HB c; c.f = (_Float16)(f - fh);
    r.l = c.u;
    return r;
}
__device__ __forceinline__ float clampl(float x) {
    return fminf(fmaxf(x, -LAMBD), LAMBD);
}
__device__ __forceinline__ float4 cvt4h(const unsigned short* p) {
    const us4 u = *(const us4*)p;
    HB a, b, c, d;
    a.u = u.x; b.u = u.y; c.u = u.z; d.u = u.w;
    float4 f;
    f.x = (float)a.f; f.y = (float)b.f; f.z = (float)c.f; f.w = (float)d.f;
    return f;
}

// ---------------------------------------------------------------------------
// Split-K small GEMM (768x768 out, fp16 3-term), 64x64 tile, reg-prefetch,
// single LDS buffer + transposed (coalesced) epilogue. Grid: (12, 12, KS).
// (R12-proven form, unchanged.)
// ---------------------------------------------------------------------------
template<int APRE>
__global__ __launch_bounds__(256)
void gemm_sk(const float* __restrict__ A,
             const unsigned short* __restrict__ Ah,
             const unsigned short* __restrict__ Al,
             int lda,
             const unsigned short* __restrict__ Bh,
             const unsigned short* __restrict__ Bl,
             int ldb,
             float* __restrict__ P, int Kper)
{
    __shared__ __align__(16) char smem[20480];
    unsigned short (*AsH)[40] = (unsigned short (*)[40])(smem);
    unsigned short (*AsL)[40] = (unsigned short (*)[40])(smem + 5120);
    unsigned short (*BsH)[40] = (unsigned short (*)[40])(smem + 10240);
    unsigned short (*BsL)[40] = (unsigned short (*)[40])(smem + 15360);

    const int tid  = threadIdx.x;
    const int brow = blockIdx.y * 64;
    const int bcol = blockIdx.x * 64;
    const int koff = blockIdx.z * Kper;
    const int wave = tid >> 6, lane = tid & 63;
    const int wr = wave >> 1, wc = wave & 1;
    const int lrow = lane & 15, kg = lane >> 4;

    const int sk4  = (tid & 7) << 2;

    us4   rAh[2], rAl[2], rBh[2], rBl[2];
    float4 rAf[2];

    auto LOAD = [&](int k0) {
        #pragma unroll
        for (int p = 0; p < 2; ++p) {
            const int row = (p * 256 + tid) >> 3;
            const size_t ga = (size_t)(brow + row) * lda + k0 + sk4;
            const size_t gb = (size_t)(bcol + row) * ldb + k0 + sk4;
            if constexpr (APRE) {
                rAh[p] = *(const us4*)(Ah + ga);
                rAl[p] = *(const us4*)(Al + ga);
            } else {
                rAf[p] = *(const float4*)(A + ga);
            }
            rBh[p] = *(const us4*)(Bh + gb);
            rBl[p] = *(const us4*)(Bl + gb);
        }
    };
    auto STORE = [&]() {
        #pragma unroll
        for (int p = 0; p < 2; ++p) {
            const int row = (p * 256 + tid) >> 3;
            if constexpr (APRE) {
                *(us4*)&AsH[row][sk4] = rAh[p];
                *(us4*)&AsL[row][sk4] = rAl[p];
            } else {
                const HL sx = split2h(rAf[p].x), sy = split2h(rAf[p].y);
                const HL sz = split2h(rAf[p].z), sw = split2h(rAf[p].w);
                us4 h, l;
                h.x = sx.h; l.x = sx.l; h.y = sy.h; l.y = sy.l;
                h.z = sz.h; l.z = sz.l; h.w = sw.h; l.w = sw.l;
                *(us4*)&AsH[row][sk4] = h;
                *(us4*)&AsL[row][sk4] = l;
            }
            *(us4*)&BsH[row][sk4] = rBh[p];
            *(us4*)&BsL[row][sk4] = rBl[p];
        }
    };

    f32x4 acc[2][2];
    #pragma unroll
    for (int m = 0; m < 2; ++m)
        #pragma unroll
        for (int n = 0; n < 2; ++n)
            #pragma unroll
            for (int q = 0; q < 4; ++q) acc[m][n][q] = 0.0f;

    const int NK = Kper / 32;
    LOAD(koff);
    STORE();
    __syncthreads();

    for (int ki = 0; ki < NK; ++ki) {
        if (ki + 1 < NK) LOAD(koff + (ki + 1) * 32);

        half8 ahi[2], alo[2], bhi[2], blo[2];
        #pragma unroll
        for (int m = 0; m < 2; ++m) {
            const int r = wr * 32 + m * 16 + lrow;
            ahi[m] = *(const half8*)&AsH[r][kg * 8];
            alo[m] = *(const half8*)&AsL[r][kg * 8];
        }
        #pragma unroll
        for (int n = 0; n < 2; ++n) {
            const int c = wc * 32 + n * 16 + lrow;
            bhi[n] = *(const half8*)&BsH[c][kg * 8];
            blo[n] = *(const half8*)&BsL[c][kg * 8];
        }
        #pragma unroll
        for (int m = 0; m < 2; ++m)
            #pragma unroll
            for (int n = 0; n < 2; ++n) {
                acc[m][n] = __builtin_amdgcn_mfma_f32_16x16x32_f16(ahi[m], bhi[n], acc[m][n], 0, 0, 0);
                acc[m][n] = __builtin_amdgcn_mfma_f32_16x16x32_f16(ahi[m], blo[n], acc[m][n], 0, 0, 0);
                acc[m][n] = __builtin_amdgcn_mfma_f32_16x16x32_f16(alo[m], bhi[n], acc[m][n], 0, 0, 0);
            }
        __syncthreads();
        if (ki + 1 < NK) { STORE(); __syncthreads(); }
    }

    // transposed epilogue: acc -> LDS [64][65] -> coalesced float4 rows
    float* eb = (float*)smem;
    #pragma unroll
    for (int m = 0; m < 2; ++m)
        #pragma unroll
        for (int n = 0; n < 2; ++n)
            #pragma unroll
            for (int r = 0; r < 4; ++r)
                eb[(wr * 32 + m * 16 + kg * 4 + r) * 65 + wc * 32 + n * 16 + lrow] = acc[m][n][r];
    __syncthreads();
    float* Pk = P + (size_t)blockIdx.z * NN_ * NN_;
    #pragma unroll
    for (int j = 0; j < 4; ++j) {
        const int row = wave * 16 + j * 4 + (lane >> 4);
        const int col = (lane & 15) * 4;
        const float4 v = *(const float4*)&eb[row * 65 + col];
        *(float4*)(Pk + (size_t)(brow + row) * NN_ + bcol + col) = v;
    }
}

// Reduce 4 split-K partials with epilogue. MODE: 0 plain, 1 +I, 2 2*E1-sum.
template<int MODE>
__global__ __launch_bounds__(256)
void red_ns(const float* __restrict__ P,
            const float* __restrict__ E1,
            float* __restrict__ C,
            unsigned short* __restrict__ Ch,
            unsigned short* __restrict__ Cl)
{
    const size_t i4 = ((size_t)blockIdx.x * 256 + threadIdx.x) * 4;
    const size_t sz = (size_t)NN_ * NN_;
    float4 s = *(const float4*)(P + i4);
    const float4 s1 = *(const float4*)(P + sz + i4);
    const float4 s2 = *(const float4*)(P + 2 * sz + i4);
    const float4 s3 = *(const float4*)(P + 3 * sz + i4);
    s.x = (s.x + s1.x) + (s2.x + s3.x);
    s.y = (s.y + s1.y) + (s2.y + s3.y);
    s.z = (s.z + s1.z) + (s2.z + s3.z);
    s.w = (s.w + s1.w) + (s2.w + s3.w);
    float v[4] = {s.x, s.y, s.z, s.w};
    if constexpr (MODE == 1) {
        const int row = (int)(i4 / NN_);
        const int col = (int)(i4 - (size_t)row * NN_);
        #pragma unroll
        for (int j = 0; j < 4; ++j) if (row == col + j) v[j] += 1.0f;
    }
    if constexpr (MODE == 2) {
        const float4 e = *(const float4*)(E1 + i4);
        v[0] = 2.0f * e.x - v[0]; v[1] = 2.0f * e.y - v[1];
        v[2] = 2.0f * e.z - v[2]; v[3] = 2.0f * e.w - v[3];
    }
    float4 o; o.x = v[0]; o.y = v[1]; o.z = v[2]; o.w = v[3];
    *(float4*)(C + i4) = o;
    us4 h, l;
    const HL a = split2h(v[0]), b = split2h(v[1]);
    const HL c = split2h(v[2]), d = split2h(v[3]);
    h.x = a.h; l.x = a.l; h.y = b.h; l.y = b.l;
    h.z = c.h; l.z = c.l; h.w = d.h; l.w = d.l;
    *(us4*)(Ch + i4) = h;
    *(us4*)(Cl + i4) = l;
}

// ---------------------------------------------------------------------------
// Big fp16 GEMM: 64x64 tile, 4 waves (32x32), BK=64 (2 MFMA sub-steps per
// barrier pair), reg-prefetch, single LDS buffer + transposed epilogue.
// AMODE: 0 f32 A -> cvt; 1 pre-cvt fp16 (Ah); 4 fp16 pair Ah/Ah+psz summed.
// BS: 1 = B single fp16 (Bh only); 0 = B 2-term h/l.
// EPI: 0 C=acc f32 (+EMIT); 3 ADMM w-update on SINGLE-fp16 state streams;
//      4 fp16 partial -> Y2[cks*ks+gi].
// EMIT: 0 none, 1 Y2=fp16(acc), 2 EH/EL=split(acc), 4 Y2+EHonly=fp16(acc), NO C.
// Grid: flat NBM*NBN*KS; per-XCD 2D patch PM x PN for L2 reuse.
// ---------------------------------------------------------------------------
template<int NBM, int NBN, int KS, int PM, int PN, int AMODE, int BS, int EPI, int EMIT, int LASTZ>
__global__ __launch_bounds__(256)
void gemm_big(const float* __restrict__ A,
              const unsigned short* __restrict__ Ah,
              int lda, size_t psz,
              const unsigned short* __restrict__ Bh,
              const unsigned short* __restrict__ Bl,
              int ldb,
              float* __restrict__ C, int ldc, size_t cks, int Kper,
              const unsigned short* __restrict__ F1h,
              unsigned short* __restrict__ Wh,
              float* __restrict__ OutZ,
              unsigned short* __restrict__ Y2,
              unsigned short* __restrict__ EH,
              unsigned short* __restrict__ EL)
{
    static_assert(NBM % PM == 0 && NBN % PN == 0, "patch divides grid");
    constexpr int XM = NBM / PM, XN = NBN / PN;
    static_assert(XM * XN * KS == 8, "patches x KS must equal 8 XCDs");
    static_assert(PM * PN == (NBM * NBN * KS) / 8, "slot count");

    // LDS: A[64][72] fp16 (9216B) + B h (+ l) [64][72]; epilogue needs 16640B
    constexpr int SMB_STAGE = (BS ? 2 : 3) * 9216;
    constexpr int SMB = SMB_STAGE > 16640 ? SMB_STAGE : 16640;
    __shared__ __align__(16) char smem[SMB];
    unsigned short (*AsH)[72] = (unsigned short (*)[72])(smem);
    unsigned short (*BsH)[72] = (unsigned short (*)[72])(smem + 9216);
    unsigned short (*BsL)[72] = (unsigned short (*)[72])(smem + 18432);

    const int bid  = blockIdx.x;
    const int xcd  = bid & 7;
    const int slot = bid >> 3;
    const int ks   = xcd % KS;
    const int rest = xcd / KS;
    const int xn   = rest % XN;
    const int xm   = rest / XN;
    const int m_   = xm * PM + slot / PN;
    const int n_   = xn * PN + slot % PN;
    const int brow = m_ * 64;
    const int bcol = n_ * 64;
    const int koff = ks * Kper;

    const int tid  = threadIdx.x;
    const int wave = tid >> 6, lane = tid & 63;
    const int wr = wave >> 1, wc = wave & 1;
    const int lrow = lane & 15, kg = lane >> 4;

    const int srow = tid >> 2, sk16 = (tid & 3) << 4;   // 16 fp16 per thread

    uint4  pA0, pA1, pA2, pA3, pB0, pB1, pB2, pB3;
    float4 pF[4];

    auto LOAD = [&](int k0) {
        const size_t ga = (size_t)(brow + srow) * lda + k0 + sk16;
        if constexpr (AMODE == 1) {
            pA0 = *(const uint4*)(Ah + ga);
            pA1 = *(const uint4*)(Ah + ga + 8);
        } else if constexpr (AMODE == 4) {
            pA0 = *(const uint4*)(Ah + ga);
            pA1 = *(const uint4*)(Ah + ga + 8);
            pA2 = *(const uint4*)(Ah + ga + psz);
            pA3 = *(const uint4*)(Ah + ga + psz + 8);
        } else {
            pF[0] = *(const float4*)(A + ga);
            pF[1] = *(const float4*)(A + ga + 4);
            pF[2] = *(const float4*)(A + ga + 8);
            pF[3] = *(const float4*)(A + ga + 12);
        }
        const size_t gb = (size_t)(bcol + srow) * ldb + k0 + sk16;
        pB0 = *(const uint4*)(Bh + gb);
        pB1 = *(const uint4*)(Bh + gb + 8);
        if constexpr (!BS) {
            pB2 = *(const uint4*)(Bl + gb);
            pB3 = *(const uint4*)(Bl + gb + 8);
        }
    };
    auto STORE = [&]() {
        if constexpr (AMODE == 1) {
            *(uint4*)&AsH[srow][sk16]     = pA0;
            *(uint4*)&AsH[srow][sk16 + 8] = pA1;
        } else if constexpr (AMODE == 4) {
            half8 s0 = *(half8*)&pA0 + *(half8*)&pA2;
            half8 s1 = *(half8*)&pA1 + *(half8*)&pA3;
            *(half8*)&AsH[srow][sk16]     = s0;
            *(half8*)&AsH[srow][sk16 + 8] = s1;
        } else {
            half8 h0, h1;
            h0[0] = (_Float16)pF[0].x; h0[1] = (_Float16)pF[0].y;
            h0[2] = (_Float16)pF[0].z; h0[3] = (_Float16)pF[0].w;
            h0[4] = (_Float16)pF[1].x; h0[5] = (_Float16)pF[1].y;
            h0[6] = (_Float16)pF[1].z; h0[7] = (_Float16)pF[1].w;
            h1[0] = (_Float16)pF[2].x; h1[1] = (_Float16)pF[2].y;
            h1[2] = (_Float16)pF[2].z; h1[3] = (_Float16)pF[2].w;
            h1[4] = (_Float16)pF[3].x; h1[5] = (_Float16)pF[3].y;
            h1[6] = (_Float16)pF[3].z; h1[7] = (_Float16)pF[3].w;
            *(half8*)&AsH[srow][sk16]     = h0;
            *(half8*)&AsH[srow][sk16 + 8] = h1;
        }
        *(uint4*)&BsH[srow][sk16]     = pB0;
        *(uint4*)&BsH[srow][sk16 + 8] = pB1;
        if constexpr (!BS) {
            *(uint4*)&BsL[srow][sk16]     = pB2;
            *(uint4*)&BsL[srow][sk16 + 8] = pB3;
        }
    };

    f32x4 acc[2][2];
    #pragma unroll
    for (int m = 0; m < 2; ++m)
        #pragma unroll
        for (int n = 0; n < 2; ++n)
            #pragma unroll
            for (int q = 0; q < 4; ++q) acc[m][n][q] = 0.0f;

    const int NK = Kper / 64;
    LOAD(koff);
    STORE();
    __syncthreads();

    for (int ki = 0; ki < NK; ++ki) {
        if (ki + 1 < NK) LOAD(koff + (ki + 1) * 64);

        #pragma unroll
        for (int kk = 0; kk < 2; ++kk) {
            const int kc = kk * 32 + kg * 8;
            half8 a[2], bh[2], bl[2];
            #pragma unroll
            for (int m = 0; m < 2; ++m)
                a[m] = *(const half8*)&AsH[wr * 32 + m * 16 + lrow][kc];
            #pragma unroll
            for (int n = 0; n < 2; ++n) {
                const int c = wc * 32 + n * 16 + lrow;
                bh[n] = *(const half8*)&BsH[c][kc];
                if constexpr (!BS) bl[n] = *(const half8*)&BsL[c][kc];
            }
            #pragma unroll
            for (int m = 0; m < 2; ++m)
                #pragma unroll
                for (int n = 0; n < 2; ++n) {
                    acc[m][n] = __builtin_amdgcn_mfma_f32_16x16x32_f16(a[m], bh[n], acc[m][n], 0, 0, 0);
                    if constexpr (!BS)
                        acc[m][n] = __builtin_amdgcn_mfma_f32_16x16x32_f16(a[m], bl[n], acc[m][n], 0, 0, 0);
                }
        }
        __syncthreads();
        if (ki + 1 < NK) { STORE(); __syncthreads(); }
    }

    // ---- transposed epilogue: acc -> LDS [64][65] -> whole-row float4 I/O ----
    float* eb = (float*)smem;
    #pragma unroll
    for (int m = 0; m < 2; ++m)
        #pragma unroll
        for (int n = 0; n < 2; ++n)
            #pragma unroll
            for (int r = 0; r < 4; ++r)
                eb[(wr * 32 + m * 16 + kg * 4 + r) * 65 + wc * 32 + n * 16 + lrow] = acc[m][n][r];
    __syncthreads();

    #pragma unroll
    for (int j = 0; j < 4; ++j) {
        const int row = wave * 16 + j * 4 + (lane >> 4);
        const int col = (lane & 15) * 4;
        const float4 v = *(const float4*)&eb[row * 65 + col];
        const size_t gi = (size_t)(brow + row) * ldc + bcol + col;
        if constexpr (EPI == 0) {
            if constexpr (EMIT != 4)
                *(float4*)(C + cks * ks + gi) = v;
            if constexpr (EMIT == 1) {
                us4 h;
                h.x = h_bits(v.x); h.y = h_bits(v.y);
                h.z = h_bits(v.z); h.w = h_bits(v.w);
                *(us4*)(Y2 + gi) = h;
            }
            if constexpr (EMIT == 2) {
                const HL a = split2h(v.x), b = split2h(v.y);
                const HL c2 = split2h(v.z), d = split2h(v.w);
                us4 h, l;
                h.x = a.h; l.x = a.l; h.y = b.h; l.y = b.l;
                h.z = c2.h; l.z = c2.l; h.w = d.h; l.w = d.l;
                *(us4*)(EH + gi) = h;
                *(us4*)(EL + gi) = l;
            }
            if constexpr (EMIT == 4) {
                us4 h;
                h.x = h_bits(v.x); h.y = h_bits(v.y);
                h.z = h_bits(v.z); h.w = h_bits(v.w);
                *(us4*)(Y2 + gi) = h;
                *(us4*)(EH + gi) = h;
            }
        } else if constexpr (EPI == 4) {
            us4 h;
            h.x = h_bits(v.x); h.y = h_bits(v.y);
            h.z = h_bits(v.z); h.w = h_bits(v.w);
            *(us4*)(Y2 + cks * ks + gi) = h;
        } else { // EPI == 3
            const float4 f1 = cvt4h(F1h + gi);
            const float4 ww = cvt4h(Wh + gi);
            const float f1v[4] = {f1.x, f1.y, f1.z, f1.w};
            const float wwv[4] = {ww.x, ww.y, ww.z, ww.w};
            const float vv[4]  = {v.x, v.y, v.z, v.w};
            float wn[4];
            #pragma unroll
            for (int q = 0; q < 4; ++q)
                wn[q] = f1v[q] + wwv[q] - clampl(wwv[q]) - vv[q];
            if constexpr (LASTZ) {
                float4 o;
                o.x = wn[0] - clampl(wn[0]); o.y = wn[1] - clampl(wn[1]);
                o.z = wn[2] - clampl(wn[2]); o.w = wn[3] - clampl(wn[3]);
                *(float4*)(OutZ + gi) = o;
            } else {
                us4 hh, y;
                #pragma unroll
                for (int q = 0; q < 4; ++q) {
                    ((unsigned short*)&hh)[q] = h_bits(wn[q]);
                    ((unsigned short*)&y)[q]  = h_bits(f1v[q] + wn[q] - 2.0f * clampl(wn[q]));
                }
                *(us4*)(Wh + gi) = hh;
                *(us4*)(Y2 + gi) = y;
            }
        }
    }
}

// Normalize rows of weight (3072x768); emit fp16 h/l of wn and wn^T.
__global__ __launch_bounds__(256)
void rownorm_kernel(const float* __restrict__ W,
                    unsigned short* __restrict__ wnH, unsigned short* __restrict__ wnL,
                    unsigned short* __restrict__ wnTH, unsigned short* __restrict__ wnTL)
{
    __shared__ float red[256];
    const int row = blockIdx.x;
    const int t = threadIdx.x;
    const float* wr = W + (size_t)row * NN_;
    float s = 0.0f;
    for (int k = t; k < NN_; k += 256) { const float w = wr[k]; s += w * w; }
    red[t] = s; __syncthreads();
    for (int off = 128; off > 0; off >>= 1) {
        if (t < off) red[t] += red[t + off];
        __syncthreads();
    }
    const float rn = 1.0f / sqrtf(red[0]);
    for (int k = t; k < NN_; k += 256) {
        const float v = wr[k] * rn;
        const HL s2 = split2h(v);
        wnH[(size_t)row * NN_ + k] = s2.h;
        wnL[(size_t)row * NN_ + k] = s2.l;
        wnTH[(size_t)k * MM + row] = s2.h;
        wnTL[(size_t)k * MM + row] = s2.l;
    }
}

__global__ __launch_bounds__(256)
void rowabs_kernel(const float* __restrict__ G, float* __restrict__ rowsum)
{
    __shared__ float red[256];
    const int row = blockIdx.x;
    const int t = threadIdx.x;
    const float* gr = G + (size_t)row * NN_;
    float s = 0.0f;
    for (int k = t; k < NN_; k += 256) s += fabsf(gr[k]);
    red[t] = s; __syncthreads();
    for (int off = 128; off > 0; off >>= 1) {
        if (t < off) red[t] += red[t + off];
        __syncthreads();
    }
    if (t == 0) rowsum[row] = red[0];
}

__global__ __launch_bounds__(256)
void cmax_kernel(const float* __restrict__ rowsum, float* __restrict__ cbuf)
{
    __shared__ float red[256];
    const int t = threadIdx.x;
    float mx = 0.0f;
    for (int k = t; k < NN_; k += 256) mx = fmaxf(mx, rowsum[k]);
    red[t] = mx; __syncthreads();
    for (int off = 128; off > 0; off >>= 1) {
        if (t < off) red[t] = fmaxf(red[t], red[t + off]);
        __syncthreads();
    }
    if (t == 0) cbuf[0] = 2.0f / (1.0f + red[0]);
}

__global__ __launch_bounds__(256)
void initdiag_kernel(float* __restrict__ X, const float* __restrict__ c)
{
    const int idx = blockIdx.x * 256 + threadIdx.x;
    const int p = idx / NN_, q = idx - p * NN_;
    X[idx] = (p == q) ? c[0] : 0.0f;
}

// dec = p0 + p1 (float4)
__global__ __launch_bounds__(256)
void add2_kernel(const float* __restrict__ p0, size_t ps, float* __restrict__ o)
{
    const size_t i = ((size_t)blockIdx.x * 256 + threadIdx.x) * 4;
    const float4 a = *(const float4*)(p0 + i);
    const float4 b = *(const float4*)(p0 + ps + i);
    float4 v;
    v.x = a.x + b.x; v.y = a.y + b.y;
    v.z = a.z + b.z; v.w = a.w + b.w;
    *(float4*)(o + i) = v;
}

extern "C" void kernel_launch(void* const* d_in, const int* in_sizes, int n_in,
                              void* d_out, int out_size, void* d_ws, size_t ws_size,
                              hipStream_t stream)
{
    const float* x = (const float*)d_in[0];   // (2048, 768)
    const float* w = (const float*)d_in[1];   // (3072, 768)

    float* out = (float*)d_out;
    float* z   = out;                          // (2048, 3072)
    float* dec = out + (size_t)BB * MM;        // (2048, 768)

    char* wsb = (char*)d_ws;
    size_t off = 0;
    auto alloc = [&](size_t bytes) -> void* {
        void* p = wsb + off;
        off += (bytes + 255) & ~(size_t)255;
        return p;
    };
    // --- persistent ---
    unsigned short* wnH  = (unsigned short*)alloc((size_t)MM * NN_ * 2);
    unsigned short* wnL  = (unsigned short*)alloc((size_t)MM * NN_ * 2);
    unsigned short* wnTH = (unsigned short*)alloc((size_t)MM * NN_ * 2);
    unsigned short* wnTL = (unsigned short*)alloc((size_t)MM * NN_ * 2);
    unsigned short* adh  = (unsigned short*)alloc((size_t)BB * MM * 2);  // fp16 adotb
    unsigned short* wbh  = (unsigned short*)alloc((size_t)BB * MM * 2);  // fp16 w state
    unsigned short* y2h  = (unsigned short*)alloc((size_t)BB * MM * 2);
    unsigned short* QH  = (unsigned short*)alloc((size_t)NN_ * NN_ * 2);
    unsigned short* QL  = (unsigned short*)alloc((size_t)NN_ * NN_ * 2);
    unsigned short* RTH = (unsigned short*)alloc((size_t)MM * NN_ * 2);
    unsigned short* RTL = (unsigned short*)alloc((size_t)MM * NN_ * 2);
    unsigned short* Thp = (unsigned short*)alloc((size_t)2 * BB * NN_ * 2); // fp16 T partials
    // --- overlay: NS temps (dead after RT) aliased with Tp (decode partials) ---
    const size_t overlay = off;
    float* G  = (float*)alloc((size_t)NN_ * NN_ * 4);
    unsigned short* GH  = (unsigned short*)alloc((size_t)NN_ * NN_ * 2);
    unsigned short* GL  = (unsigned short*)alloc((size_t)NN_ * NN_ * 2);
    float* X0 = (float*)alloc((size_t)NN_ * NN_ * 4);
    float* X1 = (float*)alloc((size_t)NN_ * NN_ * 4);
    float* Yb = (float*)alloc((size_t)NN_ * NN_ * 4);
    unsigned short* YbH = (unsigned short*)alloc((size_t)NN_ * NN_ * 2);
    unsigned short* YbL = (unsigned short*)alloc((size_t)NN_ * NN_ * 2);
    float* rowsum = (float*)alloc(NN_ * 4);
    float* cbuf   = (float*)alloc(256);
    float* Pp = (float*)alloc((size_t)4 * NN_ * NN_ * 4);  // split-K f32 partials
    // Tp (2 x 2048x768 f32 = 12.6 MB) aliases the NS-temp region (~14.2 MB);
    // NS temps dead before first Tp use (RT GEMM f32 scratch / decode partials).
    float* Tp = (float*)(wsb + overlay);
    const size_t TPS = (size_t)BB * NN_;

    (void)hipMemsetAsync(wbh, 0, (size_t)BB * MM * sizeof(unsigned short), stream);

    const dim3 blk(256);
    const dim3 gsk(NN_ / 64, NN_ / 64, 4);
    const int  RED = (NN_ * NN_ / 4) / 256;   // 576

    rownorm_kernel<<<MM, blk, 0, stream>>>(w, wnH, wnL, wnTH, wnTL);

    // adotb = x @ wn^T (M2048 N3072 K768); emit y2_0 AND adh (fp16, no f32 C).
    gemm_big<32,48,1,8,24,0,0,0,4,0><<<1536, blk, 0, stream>>>(
        x, nullptr, NN_, 0, wnH, wnL, NN_, nullptr, MM, 0, NN_,
        nullptr, nullptr, nullptr, y2h, adh, nullptr);

    // G = wn^T wn + I (768x768, K=3072), split-K=4 + reduce(+I, split)
    gemm_sk<1><<<gsk, blk, 0, stream>>>(
        nullptr, wnTH, wnTL, MM, wnTH, wnTL, MM, Pp, MM / 4);
    red_ns<1><<<RED, blk, 0, stream>>>(Pp, nullptr, G, GH, GL);

    rowabs_kernel<<<NN_, blk, 0, stream>>>(G, rowsum);
    cmax_kernel<<<1, blk, 0, stream>>>(rowsum, cbuf);
    initdiag_kernel<<<(NN_ * NN_) / 256, blk, 0, stream>>>(X0, cbuf);

    // Newton-Schulz X <- 2X - XGX, 7 iterations, split-K=4 per GEMM
    float* Xc = X0;
    float* Xn = X1;
    for (int it = 0; it < 7; ++it) {
        gemm_sk<0><<<gsk, blk, 0, stream>>>(
            Xc, nullptr, nullptr, NN_, GH, GL, NN_, Pp, NN_ / 4);
        red_ns<0><<<RED, blk, 0, stream>>>(Pp, nullptr, Yb, YbH, YbL);
        gemm_sk<0><<<gsk, blk, 0, stream>>>(
            Xc, nullptr, nullptr, NN_, YbH, YbL, NN_, Pp, NN_ / 4);
        red_ns<2><<<RED, blk, 0, stream>>>(Pp, Xc, Xn, QH, QL);
        float* t = Xc; Xc = Xn; Xn = t;
    }
    // QH/QL = fp16 split of G^{-1}

    // RT = wn @ Ginv (M3072 N768 K768); emit RTH/RTL (f32 scratch to Tp). B 2-term.
    gemm_big<48,12,1,12,6,1,0,0,2,0><<<576, blk, 0, stream>>>(
        nullptr, wnH, NN_, 0, QH, QL, NN_, Tp, NN_, 0, NN_,
        nullptr, nullptr, nullptr, nullptr, RTH, RTL);

    // ADMM loop: T = y2 @ wn -> fp16 partials Thp (KS=2, B single fp16);
    // w-update: A = Thp pair summed (AMODE=4), B = RT single fp16,
    //           state streams adh/wbh single fp16.
    for (int it = 0; it < 20; ++it) {
        gemm_big<32,12,2,16,6,1,1,4,0,0><<<768, blk, 0, stream>>>(
            nullptr, y2h, MM, 0, wnTH, nullptr, MM, nullptr, NN_, TPS, MM / 2,
            nullptr, nullptr, nullptr, Thp, nullptr, nullptr);
        if (it < 19) {
            gemm_big<32,48,1,8,24,4,1,3,0,0><<<1536, blk, 0, stream>>>(
                nullptr, Thp, NN_, TPS, RTH, nullptr, NN_, nullptr, MM, 0, NN_,
                adh, wbh, nullptr, y2h, nullptr, nullptr);
        } else {
            gemm_big<32,48,1,8,24,4,1,3,0,1><<<1536, blk, 0, stream>>>(
                nullptr, Thp, NN_, TPS, RTH, nullptr, NN_, nullptr, MM, 0, NN_,
                adh, wbh, z, y2h, nullptr, nullptr);
        }
    }

    // decoded = z @ wn (M2048 N768 K3072), KS=2 f32 partials + reduce. B 2-term.
    gemm_big<32,12,2,16,6,0,0,0,0,0><<<768, blk, 0, stream>>>(
        z, nullptr, MM, 0, wnTH, wnTL, MM, Tp, NN_, TPS, MM / 2,
        nullptr, nullptr, nullptr, nullptr, nullptr, nullptr);
    add2_kernel<<<(BB * NN_ / 4) / 256, blk, 0, stream>>>(Tp, TPS, dec);
}